// Round 4
// baseline (243.989 us; speedup 1.0000x reference)
//
#include <hip/hip_runtime.h>
#include <hip/hip_bf16.h>
#include <stdint.h>

// Problem constants
static constexpr int kB = 4;
static constexpr int kT = 2048;
static constexpr int kE = 1024;
static constexpr int kH = 16;
static constexpr int kS = 64;          // head dim
static constexpr int kRows = kB * kT;  // 8192

typedef __attribute__((ext_vector_type(4)))  float    f32x4;
typedef __attribute__((ext_vector_type(16))) float    f32x16;
typedef __attribute__((ext_vector_type(4)))  float    float4v;
typedef __attribute__((ext_vector_type(8)))  __bf16   bf16x8;
typedef __attribute__((ext_vector_type(8)))  short    short8v;
typedef __attribute__((ext_vector_type(4)))  short    short4v;
typedef __attribute__((ext_vector_type(2)))  unsigned u32x2;

typedef const __attribute__((address_space(1))) void gvoid_t;
typedef __attribute__((address_space(3))) void lvoid_t;

__device__ __forceinline__ short f2bf(float f) {
  union { float f; unsigned u; } c; c.f = f;
  unsigned r = (c.u + 0x7FFFu + ((c.u >> 16) & 1u)) >> 16;
  return (short)(r & 0xFFFFu);
}

__device__ __forceinline__ short bfc(float f) {
  union { __bf16 b; short s; } u; u.b = (__bf16)f; return u.s;
}

// v_cvt_pk_bf16_f32: D[15:0]=bf16(lo), D[31:16]=bf16(hi).
__device__ __forceinline__ unsigned cvt_pk(float lo, float hi) {
  unsigned r;
  asm("v_cvt_pk_bf16_f32 %0, %1, %2" : "=v"(r) : "v"(lo), "v"(hi));
  return r;
}

// v_permlane32_swap_b32: a' = [a.lo, b.lo], b' = [a.hi, b.hi]
// (2x2 transpose of (reg, half); m214-verified arg order: (pk_low, pk_high)).
__device__ __forceinline__ void plane_swap(unsigned& a, unsigned& b) {
  asm("v_permlane32_swap_b32 %0, %1" : "+v"(a), "+v"(b));
}

#if __has_builtin(__builtin_amdgcn_exp2f)
__device__ __forceinline__ float fexp2(float x) { return __builtin_amdgcn_exp2f(x); }
#else
__device__ __forceinline__ float fexp2(float x) { return exp2f(x); }
#endif

// ---------------- convert f32 -> bf16 (vectorized) ----------------
__global__ void cvt_bf16(const float* __restrict__ in, short* __restrict__ out) {
  size_t i = (size_t)(blockIdx.x * blockDim.x + threadIdx.x) * 4;
  float4v x = *(const float4v*)(in + i);
  short4v o;
  o[0] = f2bf(x[0]); o[1] = f2bf(x[1]); o[2] = f2bf(x[2]); o[3] = f2bf(x[3]);
  *(short4v*)(out + i) = o;
}

// ---------------- transpose + convert: W[k][n] f32 -> WT[n][k] bf16 ----------------
__global__ void transpose_cvt(const float* __restrict__ W, short* __restrict__ WT) {
  __shared__ float tile[32][33];
  const int tx = threadIdx.x & 31, ty = threadIdx.x >> 5;  // 32 x 8
  const int c = blockIdx.x * 32, r = blockIdx.y * 32;
  #pragma unroll
  for (int i = ty; i < 32; i += 8)
    tile[i][tx] = W[(size_t)(r + i) * kE + c + tx];
  __syncthreads();
  #pragma unroll
  for (int i = ty; i < 32; i += 8)
    WT[(size_t)(c + i) * kE + r + tx] = f2bf(tile[tx][i]);
}

// ---------------- bf16 GEMM (m97 recipe): C = scale*(A @ BT^T) (+bias) ----------------
template<int OUT_BF16>
__global__ __launch_bounds__(256)
void gemm_bt(const short* __restrict__ A, const short* __restrict__ BT,
             void* __restrict__ Cout, const float* __restrict__ bias,
             float scale, int M, int N, int K) {
  __shared__ short As[128 * 64];
  __shared__ short Bs[128 * 64];
  const int tid = threadIdx.x;
  const int w = tid >> 6, lane = tid & 63;
  const int g = lane >> 4, lr = lane & 15;
  const int bid = blockIdx.x;
  const int id = (bid & 7) * 64 + (bid >> 3);   // XCD swizzle (512 % 8 == 0)
  const int n0 = (id & 7) * 128, m0 = (id >> 3) * 128;
  const int wr = w >> 1, wc = w & 1;
  const int srow = lane >> 3, sch = lane & 7;
  const int swz = lr & 7;

  f32x4 acc[4][4];
  #pragma unroll
  for (int m = 0; m < 4; ++m)
    #pragma unroll
    for (int n = 0; n < 4; ++n)
      #pragma unroll
      for (int r = 0; r < 4; ++r) acc[m][n][r] = 0.f;

  for (int kt = 0; kt < K; kt += 64) {
    #pragma unroll
    for (int i = 0; i < 4; ++i) {
      const int slot = w * 4 + i;
      const int row = slot * 8 + srow;
      const int sc = sch ^ srow;   // source chunk pre-swizzle
      __builtin_amdgcn_global_load_lds(
          (gvoid_t*)(A + (size_t)(m0 + row) * K + kt + 8 * sc),
          (lvoid_t*)(As + slot * 512), 16, 0, 0);
      __builtin_amdgcn_global_load_lds(
          (gvoid_t*)(BT + (size_t)(n0 + row) * K + kt + 8 * sc),
          (lvoid_t*)(Bs + slot * 512), 16, 0, 0);
    }
    __syncthreads();
    #pragma unroll
    for (int kk = 0; kk < 2; ++kk) {
      bf16x8 af[4], bfr[4];
      #pragma unroll
      for (int m = 0; m < 4; ++m)
        af[m] = *(const bf16x8*)(As + (wr * 64 + m * 16 + lr) * 64 + (((4 * kk + g) ^ swz) << 3));
      #pragma unroll
      for (int n = 0; n < 4; ++n)
        bfr[n] = *(const bf16x8*)(Bs + (wc * 64 + n * 16 + lr) * 64 + (((4 * kk + g) ^ swz) << 3));
      __builtin_amdgcn_s_setprio(1);
      #pragma unroll
      for (int m = 0; m < 4; ++m)
        #pragma unroll
        for (int n = 0; n < 4; ++n)
          acc[m][n] = __builtin_amdgcn_mfma_f32_16x16x32_bf16(af[m], bfr[n], acc[m][n], 0, 0, 0);
      __builtin_amdgcn_s_setprio(0);
    }
    __syncthreads();
  }

  const int crow = m0 + wr * 64, ccol = n0 + wc * 64;
  if (OUT_BF16) {
    short* C = (short*)Cout;
    #pragma unroll
    for (int m = 0; m < 4; ++m)
      #pragma unroll
      for (int n = 0; n < 4; ++n)
        #pragma unroll
        for (int r = 0; r < 4; ++r)
          C[(size_t)(crow + m * 16 + 4 * g + r) * N + ccol + n * 16 + lr] =
              bfc(acc[m][n][r] * scale);
  } else {
    float* C = (float*)Cout;
    float bv[4];
    #pragma unroll
    for (int n = 0; n < 4; ++n) bv[n] = bias ? bias[ccol + n * 16 + lr] : 0.f;
    #pragma unroll
    for (int m = 0; m < 4; ++m)
      #pragma unroll
      for (int n = 0; n < 4; ++n)
        #pragma unroll
        for (int r = 0; r < 4; ++r)
          C[(size_t)(crow + m * 16 + 4 * g + r) * N + ccol + n * 16 + lr] =
              acc[m][n][r] * scale + bv[n];
  }
}

// ---------------- flash attention; V == K (faithful to reference bug) ----------------
// 32x32 swapped structure (m214): S^T = mfma(K, Q^T) so each lane owns one
// q-column; P -> PV B-fragments built in-register via cvt_pk + permlane32_swap
// (no P LDS). K A-fragments read direct from global (L2-resident, prefetched
// one tile ahead). Only V^T (= K^T) staged in LDS, double-buffered, XOR-swz.
// Q pre-scaled by E^-0.5 * log2(e).  4 waves x 32 q = QBLK 128, KVBLK 64.
__global__ __launch_bounds__(256, 2)
void attn_kernel(const short* __restrict__ Qb, const short* __restrict__ Kb,
                 short* __restrict__ AO) {
  __shared__ short Vt[2][64 * 64];   // 16 KB

  const int tid = threadIdx.x;
  const int w = tid >> 6, lane = tid & 63;
  const int l31 = lane & 31, hi = lane >> 5;
  const int swz = l31 & 7;
  const int bid = blockIdx.x;
  const int id = (bid & 7) * 128 + (bid >> 3);  // XCD swizzle (1024 % 8 == 0)
  const int q0 = (id & 15) * 128;
  const int bh = id >> 4;
  const size_t base = (size_t)(bh >> 4) * kT * kE + (size_t)(bh & 15) * kS;
  const short* Kbh = Kb + base;

  // Q B-fragments: col = q = l31, k = hi*8+j, ks over d
  bf16x8 qB[4];
  #pragma unroll
  for (int ks = 0; ks < 4; ++ks)
    qB[ks] = *(const bf16x8*)(Qb + base +
        (size_t)(q0 + w * 32 + l31) * kE + ks * 16 + hi * 8);

  f32x16 oacc[2];
  #pragma unroll
  for (int sf = 0; sf < 2; ++sf)
    #pragma unroll
    for (int r = 0; r < 16; ++r) oacc[sf][r] = 0.f;
  float lsum = 0.f, mrow = -1e30f;

  // prologue: issue tile-0 loads (V-stage regs + K A-frags)
  short8v vr0 = *(const short8v*)(Kbh + (size_t)lane * kE + 8 * w);
  short8v vr1 = *(const short8v*)(Kbh + (size_t)lane * kE + 8 * (4 + w));
  bf16x8 kf[2][4];
  #pragma unroll
  for (int kvf = 0; kvf < 2; ++kvf)
    #pragma unroll
    for (int ks = 0; ks < 4; ++ks)
      kf[kvf][ks] = *(const bf16x8*)(Kbh +
          (size_t)(kvf * 32 + l31) * kE + ks * 16 + hi * 8);

  for (int t = 0; t < 32; ++t) {
    short* VtC = &Vt[t & 1][0];

    // ---- stage V^T (=K^T) from regs, chunk-swizzled: phys = (kv/8) ^ (s&7) ----
    #pragma unroll
    for (int p = 0; p < 2; ++p) {
      const short8v v = p ? vr1 : vr0;
      const int s0 = 8 * (p * 4 + w);
      #pragma unroll
      for (int j = 0; j < 8; ++j)
        VtC[(s0 + j) * 64 + (((lane >> 3) ^ j) << 3) + (lane & 7)] = v[j];
    }
    __syncthreads();

    // ---- S^T = K Q^T (32x32x16) ----
    f32x16 sacc[2];
    #pragma unroll
    for (int kvf = 0; kvf < 2; ++kvf)
      #pragma unroll
      for (int r = 0; r < 16; ++r) sacc[kvf][r] = 0.f;
    __builtin_amdgcn_s_setprio(1);
    #pragma unroll
    for (int ks = 0; ks < 4; ++ks) {
      sacc[0] = __builtin_amdgcn_mfma_f32_32x32x16_bf16(kf[0][ks], qB[ks], sacc[0], 0, 0, 0);
      sacc[1] = __builtin_amdgcn_mfma_f32_32x32x16_bf16(kf[1][ks], qB[ks], sacc[1], 0, 0, 0);
    }
    __builtin_amdgcn_s_setprio(0);

    // ---- prefetch tile t+1 (overlaps softmax + PV) ----
    if (t < 31) {
      const short* kbn = Kbh + (size_t)(t + 1) * 64 * kE;
      vr0 = *(const short8v*)(kbn + (size_t)lane * kE + 8 * w);
      vr1 = *(const short8v*)(kbn + (size_t)lane * kE + 8 * (4 + w));
      #pragma unroll
      for (int kvf = 0; kvf < 2; ++kvf)
        #pragma unroll
        for (int ks = 0; ks < 4; ++ks)
          kf[kvf][ks] = *(const bf16x8*)(kbn +
              (size_t)(kvf * 32 + l31) * kE + ks * 16 + hi * 8);
    }

    // ---- online softmax (lane owns q-col l31; rows kv in regs) ----
    float tmax = sacc[0][0];
    #pragma unroll
    for (int kvf = 0; kvf < 2; ++kvf)
      #pragma unroll
      for (int r = 0; r < 16; ++r)
        if (kvf | r) tmax = fmaxf(tmax, sacc[kvf][r]);
    tmax = fmaxf(tmax, __shfl_xor(tmax, 32));
    if (!__all(tmax <= mrow + 8.f)) {
      const float mn = fmaxf(mrow, tmax);
      const float a = fexp2(mrow - mn);
      mrow = mn;
      lsum *= a;
      #pragma unroll
      for (int sf = 0; sf < 2; ++sf)
        #pragma unroll
        for (int r = 0; r < 16; ++r) oacc[sf][r] *= a;
    }

    // ---- P = exp2(S^T - m); build PV B-frags in-register (T12) ----
    union { unsigned u[4]; bf16x8 v; } pf[4];
    #pragma unroll
    for (int kvf = 0; kvf < 2; ++kvf) {
      float pe[16];
      #pragma unroll
      for (int r = 0; r < 16; ++r) {
        pe[r] = fexp2(sacc[kvf][r] - mrow);
        lsum += pe[r];
      }
      #pragma unroll
      for (int sub = 0; sub < 2; ++sub) {
        unsigned a0 = cvt_pk(pe[8 * sub + 0], pe[8 * sub + 1]);
        unsigned b0 = cvt_pk(pe[8 * sub + 4], pe[8 * sub + 5]);
        plane_swap(a0, b0);   // a0 = words k0-1, b0 = words k4-5
        unsigned a1 = cvt_pk(pe[8 * sub + 2], pe[8 * sub + 3]);
        unsigned b1 = cvt_pk(pe[8 * sub + 6], pe[8 * sub + 7]);
        plane_swap(a1, b1);   // a1 = k2-3, b1 = k6-7
        pf[2 * kvf + sub].u[0] = a0;
        pf[2 * kvf + sub].u[1] = a1;
        pf[2 * kvf + sub].u[2] = b0;
        pf[2 * kvf + sub].u[3] = b1;
      }
    }

    // ---- O^T += V^T P^T ----
    #pragma unroll
    for (int ks = 0; ks < 4; ++ks) {
      const int pc = ((2 * ks + hi) ^ swz) << 3;
      bf16x8 vf0 = *(const bf16x8*)(VtC + (l31)      * 64 + pc);
      bf16x8 vf1 = *(const bf16x8*)(VtC + (32 + l31) * 64 + pc);
      __builtin_amdgcn_s_setprio(1);
      oacc[0] = __builtin_amdgcn_mfma_f32_32x32x16_bf16(vf0, pf[ks].v, oacc[0], 0, 0, 0);
      oacc[1] = __builtin_amdgcn_mfma_f32_32x32x16_bf16(vf1, pf[ks].v, oacc[1], 0, 0, 0);
      __builtin_amdgcn_s_setprio(0);
    }
  }

  __syncthreads();   // all PV reads done before reusing LDS for O transpose

  // ---- epilogue: O = O^T / l via LDS transpose, coalesced 128B stores ----
  const float ltot = lsum + __shfl_xor(lsum, 32);
  const float inv = 1.f / ltot;
  short* Ot = &Vt[0][0] + w * 2048;   // 32 q x 64 s per wave
  #pragma unroll
  for (int sf = 0; sf < 2; ++sf)
    #pragma unroll
    for (int c = 0; c < 4; ++c) {
      u32x2 e;
      e[0] = cvt_pk(oacc[sf][4 * c + 0] * inv, oacc[sf][4 * c + 1] * inv);
      e[1] = cvt_pk(oacc[sf][4 * c + 2] * inv, oacc[sf][4 * c + 3] * inv);
      *(u32x2*)(Ot + l31 * 64 + sf * 32 + 8 * c + 4 * hi) = e;
    }
  #pragma unroll
  for (int i = 0; i < 8; ++i) {
    const int row = i * 4 + (lane >> 4);
    u32x2 v = *(const u32x2*)(Ot + row * 64 + (lane & 15) * 4);
    *(u32x2*)(AO + base + (size_t)(q0 + w * 32 + row) * kE + (lane & 15) * 4) = v;
  }
}

// ---------------- launch ----------------
extern "C" void kernel_launch(void* const* d_in, const int* in_sizes, int n_in,
                              void* d_out, int out_size, void* d_ws, size_t ws_size,
                              hipStream_t stream) {
  const float* x  = (const float*)d_in[0];
  const float* Wk = (const float*)d_in[1];
  const float* Wq = (const float*)d_in[2];
  const float* Wo = (const float*)d_in[3];
  const float* bo = (const float*)d_in[4];
  float* out = (float*)d_out;

  const size_t nXE = (size_t)kRows * kE;  // 8388608
  const size_t nW  = (size_t)kE * kE;     // 1048576

  short* Xb  = (short*)d_ws;
  short* Kb  = Xb  + nXE;
  short* Qb  = Kb  + nXE;
  short* WkT = Qb  + nXE;
  short* WqT = WkT + nW;
  short* WoT = WqT + nW;
  short* AO  = Xb;  // reuse: x no longer needed after projections

  cvt_bf16<<<dim3(nXE / (4 * 256)), 256, 0, stream>>>(x, Xb);
  transpose_cvt<<<dim3(32, 32), 256, 0, stream>>>(Wk, WkT);
  transpose_cvt<<<dim3(32, 32), 256, 0, stream>>>(Wq, WqT);
  transpose_cvt<<<dim3(32, 32), 256, 0, stream>>>(Wo, WoT);

  // K (=V) and Q projections; fold E^-0.5 * log2(e) into Q so softmax is exp2
  gemm_bt<1><<<dim3(512), 256, 0, stream>>>(
      Xb, WkT, (void*)Kb, nullptr, 1.0f, kRows, kE, kE);
  gemm_bt<1><<<dim3(512), 256, 0, stream>>>(
      Xb, WqT, (void*)Qb, nullptr, 0.03125f * 1.44269504f, kRows, kE, kE);

  attn_kernel<<<dim3(1024), 256, 0, stream>>>(Qb, Kb, AO);

  gemm_bt<0><<<dim3(512), 256, 0, stream>>>(
      AO, WoT, (void*)out, bo, 1.0f, kRows, kE, kE);
}

// Round 5
// 196.529 us; speedup vs baseline: 1.2415x; 1.2415x over previous
//
#include <hip/hip_runtime.h>
#include <hip/hip_bf16.h>
#include <stdint.h>

// Problem constants
static constexpr int kB = 4;
static constexpr int kT = 2048;
static constexpr int kE = 1024;
static constexpr int kH = 16;
static constexpr int kS = 64;          // head dim
static constexpr int kRows = kB * kT;  // 8192

typedef __attribute__((ext_vector_type(4)))  float    f32x4;
typedef __attribute__((ext_vector_type(16))) float    f32x16;
typedef __attribute__((ext_vector_type(4)))  float    float4v;
typedef __attribute__((ext_vector_type(8)))  __bf16   bf16x8;
typedef __attribute__((ext_vector_type(8)))  short    short8v;
typedef __attribute__((ext_vector_type(4)))  short    short4v;
typedef __attribute__((ext_vector_type(2)))  unsigned u32x2;

typedef const __attribute__((address_space(1))) void gvoid_t;
typedef __attribute__((address_space(3))) void lvoid_t;

__device__ __forceinline__ short f2bf(float f) {
  union { float f; unsigned u; } c; c.f = f;
  unsigned r = (c.u + 0x7FFFu + ((c.u >> 16) & 1u)) >> 16;
  return (short)(r & 0xFFFFu);
}

__device__ __forceinline__ short bfc(float f) {
  union { __bf16 b; short s; } u; u.b = (__bf16)f; return u.s;
}

// v_cvt_pk_bf16_f32: D[15:0]=bf16(lo), D[31:16]=bf16(hi).
__device__ __forceinline__ unsigned cvt_pk(float lo, float hi) {
  unsigned r;
  asm("v_cvt_pk_bf16_f32 %0, %1, %2" : "=v"(r) : "v"(lo), "v"(hi));
  return r;
}

// v_permlane32_swap_b32: a' = [a.lo, b.lo], b' = [a.hi, b.hi]
__device__ __forceinline__ void plane_swap(unsigned& a, unsigned& b) {
  asm("v_permlane32_swap_b32 %0, %1" : "+v"(a), "+v"(b));
}

#if __has_builtin(__builtin_amdgcn_exp2f)
__device__ __forceinline__ float fexp2(float x) { return __builtin_amdgcn_exp2f(x); }
#else
__device__ __forceinline__ float fexp2(float x) { return exp2f(x); }
#endif

// ---------------- convert f32 -> bf16 (vectorized) ----------------
__global__ void cvt_bf16(const float* __restrict__ in, short* __restrict__ out) {
  size_t i = (size_t)(blockIdx.x * blockDim.x + threadIdx.x) * 4;
  float4v x = *(const float4v*)(in + i);
  short4v o;
  o[0] = f2bf(x[0]); o[1] = f2bf(x[1]); o[2] = f2bf(x[2]); o[3] = f2bf(x[3]);
  *(short4v*)(out + i) = o;
}

// ---------------- transpose + convert: W[k][n] f32 -> WT[n][k] bf16 ----------------
__global__ void transpose_cvt(const float* __restrict__ W, short* __restrict__ WT) {
  __shared__ float tile[32][33];
  const int tx = threadIdx.x & 31, ty = threadIdx.x >> 5;  // 32 x 8
  const int c = blockIdx.x * 32, r = blockIdx.y * 32;
  #pragma unroll
  for (int i = ty; i < 32; i += 8)
    tile[i][tx] = W[(size_t)(r + i) * kE + c + tx];
  __syncthreads();
  #pragma unroll
  for (int i = ty; i < 32; i += 8)
    WT[(size_t)(c + i) * kE + r + tx] = f2bf(tile[tx][i]);
}

// ---------------- V transpose: Kb[b][t][h][s] -> KT[(b*16+h)][s][t] (bf16) ----------------
// Fully coalesced both sides (128B contiguous per 8 lanes).
__global__ __launch_bounds__(256)
void transv(const short* __restrict__ Kb, short* __restrict__ KT) {
  __shared__ short tile[64][72];
  const int tid = threadIdx.x;
  const int bh = blockIdx.y;               // b*16 + h
  const int t0 = blockIdx.x * 64;
  const size_t base = (size_t)(bh >> 4) * kT * kE + (size_t)(bh & 15) * kS;
  #pragma unroll
  for (int i = 0; i < 2; ++i) {
    const int row = i * 32 + (tid >> 3), c = (tid & 7) * 8;
    *(short8v*)&tile[row][c] =
        *(const short8v*)(Kb + base + (size_t)(t0 + row) * kE + c);
  }
  __syncthreads();
  #pragma unroll
  for (int i = 0; i < 2; ++i) {
    const int s = i * 32 + (tid >> 3), c = (tid & 7) * 8;
    short8v o;
    #pragma unroll
    for (int j = 0; j < 8; ++j) o[j] = tile[c + j][s];
    *(short8v*)(KT + ((size_t)bh * 64 + s) * kT + t0 + c) = o;
  }
}

// ---------------- bf16 GEMM (m97 recipe): C = scale*(A @ BT^T) (+bias) ----------------
template<int OUT_BF16>
__global__ __launch_bounds__(256)
void gemm_bt(const short* __restrict__ A, const short* __restrict__ BT,
             void* __restrict__ Cout, const float* __restrict__ bias,
             float scale, int M, int N, int K) {
  __shared__ short As[128 * 64];
  __shared__ short Bs[128 * 64];
  const int tid = threadIdx.x;
  const int w = tid >> 6, lane = tid & 63;
  const int g = lane >> 4, lr = lane & 15;
  const int bid = blockIdx.x;
  const int id = (bid & 7) * 64 + (bid >> 3);   // XCD swizzle (512 % 8 == 0)
  const int n0 = (id & 7) * 128, m0 = (id >> 3) * 128;
  const int wr = w >> 1, wc = w & 1;
  const int srow = lane >> 3, sch = lane & 7;
  const int swz = lr & 7;

  f32x4 acc[4][4];
  #pragma unroll
  for (int m = 0; m < 4; ++m)
    #pragma unroll
    for (int n = 0; n < 4; ++n)
      #pragma unroll
      for (int r = 0; r < 4; ++r) acc[m][n][r] = 0.f;

  for (int kt = 0; kt < K; kt += 64) {
    #pragma unroll
    for (int i = 0; i < 4; ++i) {
      const int slot = w * 4 + i;
      const int row = slot * 8 + srow;
      const int sc = sch ^ srow;   // source chunk pre-swizzle
      __builtin_amdgcn_global_load_lds(
          (gvoid_t*)(A + (size_t)(m0 + row) * K + kt + 8 * sc),
          (lvoid_t*)(As + slot * 512), 16, 0, 0);
      __builtin_amdgcn_global_load_lds(
          (gvoid_t*)(BT + (size_t)(n0 + row) * K + kt + 8 * sc),
          (lvoid_t*)(Bs + slot * 512), 16, 0, 0);
    }
    __syncthreads();
    #pragma unroll
    for (int kk = 0; kk < 2; ++kk) {
      bf16x8 af[4], bfr[4];
      #pragma unroll
      for (int m = 0; m < 4; ++m)
        af[m] = *(const bf16x8*)(As + (wr * 64 + m * 16 + lr) * 64 + (((4 * kk + g) ^ swz) << 3));
      #pragma unroll
      for (int n = 0; n < 4; ++n)
        bfr[n] = *(const bf16x8*)(Bs + (wc * 64 + n * 16 + lr) * 64 + (((4 * kk + g) ^ swz) << 3));
      __builtin_amdgcn_s_setprio(1);
      #pragma unroll
      for (int m = 0; m < 4; ++m)
        #pragma unroll
        for (int n = 0; n < 4; ++n)
          acc[m][n] = __builtin_amdgcn_mfma_f32_16x16x32_bf16(af[m], bfr[n], acc[m][n], 0, 0, 0);
      __builtin_amdgcn_s_setprio(0);
    }
    __syncthreads();
  }

  const int crow = m0 + wr * 64, ccol = n0 + wc * 64;
  if (OUT_BF16) {
    short* C = (short*)Cout;
    #pragma unroll
    for (int m = 0; m < 4; ++m)
      #pragma unroll
      for (int n = 0; n < 4; ++n)
        #pragma unroll
        for (int r = 0; r < 4; ++r)
          C[(size_t)(crow + m * 16 + 4 * g + r) * N + ccol + n * 16 + lr] =
              bfc(acc[m][n][r] * scale);
  } else {
    float* C = (float*)Cout;
    float bv[4];
    #pragma unroll
    for (int n = 0; n < 4; ++n) bv[n] = bias ? bias[ccol + n * 16 + lr] : 0.f;
    #pragma unroll
    for (int m = 0; m < 4; ++m)
      #pragma unroll
      for (int n = 0; n < 4; ++n)
        #pragma unroll
        for (int r = 0; r < 4; ++r)
          C[(size_t)(crow + m * 16 + 4 * g + r) * N + ccol + n * 16 + lr] =
              acc[m][n][r] * scale + bv[n];
  }
}

// ---------------- flash attention; V == K (faithful to reference bug) ----------------
// 32x32 swapped structure: S^T = mfma(K, Q^T), lane owns one q-column (scalar
// m/l); P -> PV B-frags in-register via cvt_pk + permlane32_swap (T12).
// ALL global->LDS staging is coalesced global_load_lds (no per-lane scatter):
// Kt [kv][s] from Kb rows, Vt [s][kv] from pre-transposed KT rows. Both
// double-buffered, XOR chunk-swizzled via pre-swizzled source, one barrier
// per tile, next-tile loads issued right after the barrier (T3-minimum).
__global__ __launch_bounds__(256, 3)
void attn_kernel(const short* Qb, const short* __restrict__ Kb,
                 const short* __restrict__ KT, short* AO) {
  __shared__ short Kt[2][64 * 64];   // 16 KB
  __shared__ short Vt[2][64 * 64];   // 16 KB

  const int tid = threadIdx.x;
  const int w = tid >> 6, lane = tid & 63;
  const int l31 = lane & 31, hi = lane >> 5;
  const int swz = l31 & 7;
  const int bid = blockIdx.x;
  const int id = (bid & 7) * 128 + (bid >> 3);  // XCD swizzle (1024 % 8 == 0)
  const int q0 = (id & 15) * 128;
  const int bh = id >> 4;                       // b*16 + h
  const size_t base = (size_t)(bh >> 4) * kT * kE + (size_t)(bh & 15) * kS;
  const short* Kbh = Kb + base;
  const short* KTbh = KT + (size_t)bh * 64 * kT;

  // staging geometry (per wave: 2 slots x {Kt,Vt})
  const int srow_lo = lane >> 3, sch = lane & 7;

  // ---- prologue: issue tile-0 staging, load Q B-fragments ----
  {
    #pragma unroll
    for (int i = 0; i < 2; ++i) {
      const int slot = w * 2 + i, row = slot * 8 + srow_lo;
      const int sc = sch ^ (row & 7);
      __builtin_amdgcn_global_load_lds(
          (gvoid_t*)(Kbh + (size_t)row * kE + 8 * sc),
          (lvoid_t*)(&Kt[0][0] + slot * 512), 16, 0, 0);
      __builtin_amdgcn_global_load_lds(
          (gvoid_t*)(KTbh + (size_t)row * kT + 8 * sc),
          (lvoid_t*)(&Vt[0][0] + slot * 512), 16, 0, 0);
    }
  }

  bf16x8 qB[4];
  #pragma unroll
  for (int ks = 0; ks < 4; ++ks)
    qB[ks] = *(const bf16x8*)(Qb + base +
        (size_t)(q0 + w * 32 + l31) * kE + ks * 16 + hi * 8);

  f32x16 oacc[2];
  #pragma unroll
  for (int sf = 0; sf < 2; ++sf)
    #pragma unroll
    for (int r = 0; r < 16; ++r) oacc[sf][r] = 0.f;
  float lsum = 0.f, mrow = -1e30f;

  for (int t = 0; t < 32; ++t) {
    __syncthreads();   // tile-t staging drained; prev-tile reads complete

    // ---- issue tile t+1 staging (hidden under this tile's compute) ----
    if (t < 31) {
      const short* kbt = Kbh + (size_t)(t + 1) * 64 * kE;
      const short* vtt = KTbh + (size_t)(t + 1) * 64;
      short* KtN = &Kt[(t + 1) & 1][0];
      short* VtN = &Vt[(t + 1) & 1][0];
      #pragma unroll
      for (int i = 0; i < 2; ++i) {
        const int slot = w * 2 + i, row = slot * 8 + srow_lo;
        const int sc = sch ^ (row & 7);
        __builtin_amdgcn_global_load_lds(
            (gvoid_t*)(kbt + (size_t)row * kE + 8 * sc),
            (lvoid_t*)(KtN + slot * 512), 16, 0, 0);
        __builtin_amdgcn_global_load_lds(
            (gvoid_t*)(vtt + (size_t)row * kT + 8 * sc),
            (lvoid_t*)(VtN + slot * 512), 16, 0, 0);
      }
    }

    const short* KtC = &Kt[t & 1][0];
    const short* VtC = &Vt[t & 1][0];

    // ---- S^T = K Q^T (32x32x16), K A-frags from LDS ----
    f32x16 sacc[2];
    #pragma unroll
    for (int kvf = 0; kvf < 2; ++kvf)
      #pragma unroll
      for (int r = 0; r < 16; ++r) sacc[kvf][r] = 0.f;
    #pragma unroll
    for (int ks = 0; ks < 4; ++ks) {
      const int pc = ((2 * ks + hi) ^ swz) << 3;
      bf16x8 kf0 = *(const bf16x8*)(KtC + (l31)      * 64 + pc);
      bf16x8 kf1 = *(const bf16x8*)(KtC + (32 + l31) * 64 + pc);
      __builtin_amdgcn_s_setprio(1);
      sacc[0] = __builtin_amdgcn_mfma_f32_32x32x16_bf16(kf0, qB[ks], sacc[0], 0, 0, 0);
      sacc[1] = __builtin_amdgcn_mfma_f32_32x32x16_bf16(kf1, qB[ks], sacc[1], 0, 0, 0);
      __builtin_amdgcn_s_setprio(0);
    }

    // ---- online softmax (lane owns q-col l31) ----
    float tmax = sacc[0][0];
    #pragma unroll
    for (int kvf = 0; kvf < 2; ++kvf)
      #pragma unroll
      for (int r = 0; r < 16; ++r)
        if (kvf | r) tmax = fmaxf(tmax, sacc[kvf][r]);
    tmax = fmaxf(tmax, __shfl_xor(tmax, 32));
    if (!__all(tmax <= mrow + 8.f)) {
      const float mn = fmaxf(mrow, tmax);
      const float a = fexp2(mrow - mn);
      mrow = mn;
      lsum *= a;
      #pragma unroll
      for (int sf = 0; sf < 2; ++sf)
        #pragma unroll
        for (int r = 0; r < 16; ++r) oacc[sf][r] *= a;
    }

    // ---- P = exp2(S^T - m); build PV B-frags in-register (T12) ----
    union { unsigned u[4]; bf16x8 v; } pf[4];
    #pragma unroll
    for (int kvf = 0; kvf < 2; ++kvf) {
      float pe[16];
      #pragma unroll
      for (int r = 0; r < 16; ++r) {
        pe[r] = fexp2(sacc[kvf][r] - mrow);
        lsum += pe[r];
      }
      #pragma unroll
      for (int sub = 0; sub < 2; ++sub) {
        unsigned a0 = cvt_pk(pe[8 * sub + 0], pe[8 * sub + 1]);
        unsigned b0 = cvt_pk(pe[8 * sub + 4], pe[8 * sub + 5]);
        plane_swap(a0, b0);
        unsigned a1 = cvt_pk(pe[8 * sub + 2], pe[8 * sub + 3]);
        unsigned b1 = cvt_pk(pe[8 * sub + 6], pe[8 * sub + 7]);
        plane_swap(a1, b1);
        pf[2 * kvf + sub].u[0] = a0;
        pf[2 * kvf + sub].u[1] = a1;
        pf[2 * kvf + sub].u[2] = b0;
        pf[2 * kvf + sub].u[3] = b1;
      }
    }

    // ---- O^T += V^T P^T ----
    #pragma unroll
    for (int ks = 0; ks < 4; ++ks) {
      const int pc = ((2 * ks + hi) ^ swz) << 3;
      bf16x8 vf0 = *(const bf16x8*)(VtC + (l31)      * 64 + pc);
      bf16x8 vf1 = *(const bf16x8*)(VtC + (32 + l31) * 64 + pc);
      __builtin_amdgcn_s_setprio(1);
      oacc[0] = __builtin_amdgcn_mfma_f32_32x32x16_bf16(vf0, pf[ks].v, oacc[0], 0, 0, 0);
      oacc[1] = __builtin_amdgcn_mfma_f32_32x32x16_bf16(vf1, pf[ks].v, oacc[1], 0, 0, 0);
      __builtin_amdgcn_s_setprio(0);
    }
  }

  __syncthreads();   // all PV reads done before reusing LDS for O transpose

  // ---- epilogue: O = O^T / l via LDS transpose, coalesced stores ----
  const float ltot = lsum + __shfl_xor(lsum, 32);
  const float inv = 1.f / ltot;
  short* Ot = &Kt[0][0] + w * 2048;   // 32 q x 64 s per wave
  #pragma unroll
  for (int sf = 0; sf < 2; ++sf)
    #pragma unroll
    for (int c = 0; c < 4; ++c) {
      u32x2 e;
      e[0] = cvt_pk(oacc[sf][4 * c + 0] * inv, oacc[sf][4 * c + 1] * inv);
      e[1] = cvt_pk(oacc[sf][4 * c + 2] * inv, oacc[sf][4 * c + 3] * inv);
      *(u32x2*)(Ot + l31 * 64 + sf * 32 + 8 * c + 4 * hi) = e;
    }
  __builtin_amdgcn_s_barrier();  // wave-local data only; barrier for LDS raw reuse timing
  #pragma unroll
  for (int i = 0; i < 8; ++i) {
    const int row = i * 4 + (lane >> 4);
    u32x2 v = *(const u32x2*)(Ot + row * 64 + (lane & 15) * 4);
    *(u32x2*)(AO + base + (size_t)(q0 + w * 32 + row) * kE + (lane & 15) * 4) = v;
  }
}

// ---------------- launch ----------------
extern "C" void kernel_launch(void* const* d_in, const int* in_sizes, int n_in,
                              void* d_out, int out_size, void* d_ws, size_t ws_size,
                              hipStream_t stream) {
  const float* x  = (const float*)d_in[0];
  const float* Wk = (const float*)d_in[1];
  const float* Wq = (const float*)d_in[2];
  const float* Wo = (const float*)d_in[3];
  const float* bo = (const float*)d_in[4];
  float* out = (float*)d_out;

  const size_t nXE = (size_t)kRows * kE;  // 8388608
  const size_t nW  = (size_t)kE * kE;     // 1048576

  short* Xb  = (short*)d_ws;
  short* Kb  = Xb  + nXE;
  short* Qb  = Kb  + nXE;
  short* WkT = Qb  + nXE;
  short* WqT = WkT + nW;
  short* WoT = WqT + nW;
  short* KTb = Xb;   // reuse: x-bf16 dead after projections
  short* AO  = Qb;   // reuse: Q read into regs before AO written (same rows)

  cvt_bf16<<<dim3(nXE / (4 * 256)), 256, 0, stream>>>(x, Xb);
  transpose_cvt<<<dim3(32, 32), 256, 0, stream>>>(Wk, WkT);
  transpose_cvt<<<dim3(32, 32), 256, 0, stream>>>(Wq, WqT);
  transpose_cvt<<<dim3(32, 32), 256, 0, stream>>>(Wo, WoT);

  // K (=V) and Q projections; fold E^-0.5 * log2(e) into Q so softmax is exp2
  gemm_bt<1><<<dim3(512), 256, 0, stream>>>(
      Xb, WkT, (void*)Kb, nullptr, 1.0f, kRows, kE, kE);
  gemm_bt<1><<<dim3(512), 256, 0, stream>>>(
      Xb, WqT, (void*)Qb, nullptr, 0.03125f * 1.44269504f, kRows, kE, kE);

  // V^T = K^T per (b,h): [bh][s][t]  (overwrites Xb)
  transv<<<dim3(kT / 64, kB * kH), 256, 0, stream>>>(Kb, KTb);

  attn_kernel<<<dim3(1024), 256, 0, stream>>>(Qb, Kb, KTb, AO);

  gemm_bt<0><<<dim3(512), 256, 0, stream>>>(
      AO, WoT, (void*)out, bo, 1.0f, kRows, kE, kE);
}

// Round 7
// 195.240 us; speedup vs baseline: 1.2497x; 1.0066x over previous
//
#include <hip/hip_runtime.h>
#include <hip/hip_bf16.h>
#include <stdint.h>

// Problem constants
static constexpr int kB = 4;
static constexpr int kT = 2048;
static constexpr int kE = 1024;
static constexpr int kH = 16;
static constexpr int kS = 64;          // head dim
static constexpr int kRows = kB * kT;  // 8192

typedef __attribute__((ext_vector_type(4)))  float    f32x4;
typedef __attribute__((ext_vector_type(16))) float    f32x16;
typedef __attribute__((ext_vector_type(4)))  float    float4v;
typedef __attribute__((ext_vector_type(8)))  __bf16   bf16x8;
typedef __attribute__((ext_vector_type(8)))  short    short8v;
typedef __attribute__((ext_vector_type(4)))  short    short4v;
typedef __attribute__((ext_vector_type(2)))  unsigned u32x2;

typedef const __attribute__((address_space(1))) void gvoid_t;
typedef __attribute__((address_space(3))) void lvoid_t;

__device__ __forceinline__ short f2bf(float f) {
  union { float f; unsigned u; } c; c.f = f;
  unsigned r = (c.u + 0x7FFFu + ((c.u >> 16) & 1u)) >> 16;
  return (short)(r & 0xFFFFu);
}

__device__ __forceinline__ short bfc(float f) {
  union { __bf16 b; short s; } u; u.b = (__bf16)f; return u.s;
}

// v_cvt_pk_bf16_f32: D[15:0]=bf16(lo), D[31:16]=bf16(hi).
__device__ __forceinline__ unsigned cvt_pk(float lo, float hi) {
  unsigned r;
  asm("v_cvt_pk_bf16_f32 %0, %1, %2" : "=v"(r) : "v"(lo), "v"(hi));
  return r;
}

// v_permlane32_swap_b32: a' = [a.lo, b.lo], b' = [a.hi, b.hi]
__device__ __forceinline__ void plane_swap(unsigned& a, unsigned& b) {
  asm("v_permlane32_swap_b32 %0, %1" : "+v"(a), "+v"(b));
}

#if __has_builtin(__builtin_amdgcn_exp2f)
__device__ __forceinline__ float fexp2(float x) { return __builtin_amdgcn_exp2f(x); }
#else
__device__ __forceinline__ float fexp2(float x) { return exp2f(x); }
#endif

// ---------------- convert f32 -> bf16 (vectorized) ----------------
__global__ void cvt_bf16(const float* __restrict__ in, short* __restrict__ out) {
  size_t i = (size_t)(blockIdx.x * blockDim.x + threadIdx.x) * 4;
  float4v x = *(const float4v*)(in + i);
  short4v o;
  o[0] = f2bf(x[0]); o[1] = f2bf(x[1]); o[2] = f2bf(x[2]); o[3] = f2bf(x[3]);
  *(short4v*)(out + i) = o;
}

// ---------------- transpose + convert: W[k][n] f32 -> WT[n][k] bf16 ----------------
__global__ void transpose_cvt(const float* __restrict__ W, short* __restrict__ WT) {
  __shared__ float tile[32][33];
  const int tx = threadIdx.x & 31, ty = threadIdx.x >> 5;  // 32 x 8
  const int c = blockIdx.x * 32, r = blockIdx.y * 32;
  #pragma unroll
  for (int i = ty; i < 32; i += 8)
    tile[i][tx] = W[(size_t)(r + i) * kE + c + tx];
  __syncthreads();
  #pragma unroll
  for (int i = ty; i < 32; i += 8)
    WT[(size_t)(c + i) * kE + r + tx] = f2bf(tile[tx][i]);
}

// ---------------- V transpose: Kb[b][t][h][s] -> KT[(b*16+h)][s][t] (bf16) ----------------
__global__ __launch_bounds__(256)
void transv(const short* __restrict__ Kb, short* __restrict__ KT) {
  __shared__ short tile[64][72];
  const int tid = threadIdx.x;
  const int bh = blockIdx.y;               // b*16 + h
  const int t0 = blockIdx.x * 64;
  const size_t base = (size_t)(bh >> 4) * kT * kE + (size_t)(bh & 15) * kS;
  #pragma unroll
  for (int i = 0; i < 2; ++i) {
    const int row = i * 32 + (tid >> 3), c = (tid & 7) * 8;
    *(short8v*)&tile[row][c] =
        *(const short8v*)(Kb + base + (size_t)(t0 + row) * kE + c);
  }
  __syncthreads();
  #pragma unroll
  for (int i = 0; i < 2; ++i) {
    const int s = i * 32 + (tid >> 3), c = (tid & 7) * 8;
    short8v o;
    #pragma unroll
    for (int j = 0; j < 8; ++j) o[j] = tile[c + j][s];
    *(short8v*)(KT + ((size_t)bh * 64 + s) * kT + t0 + c) = o;
  }
}

// ---------------- fused K+Q projection GEMM ----------------
// A[8192,1024] bf16, WkqT[2048][1024] bf16 (rows 0-1023 = Wk^T, 1024-2047 = Wq^T).
// C: n<1024 -> Kb (scale 1), else Qb (scale qs). 1024 blocks, XCD-swizzled.
__global__ __launch_bounds__(256)
void gemm_kq(const short* __restrict__ A, const short* __restrict__ BT,
             short* __restrict__ Kb, short* __restrict__ Qb, float qs) {
  __shared__ short As[128 * 64];
  __shared__ short Bs[128 * 64];
  const int tid = threadIdx.x;
  const int w = tid >> 6, lane = tid & 63;
  const int g = lane >> 4, lr = lane & 15;
  const int bid = blockIdx.x;
  const int id = (bid & 7) * 128 + (bid >> 3);   // 1024 % 8 == 0, bijective
  const int n0 = (id & 15) * 128, m0 = (id >> 4) * 128;
  const int wr = w >> 1, wc = w & 1;
  const int srow = lane >> 3, sch = lane & 7;
  const int swz = lr & 7;

  f32x4 acc[4][4];
  #pragma unroll
  for (int m = 0; m < 4; ++m)
    #pragma unroll
    for (int n = 0; n < 4; ++n)
      #pragma unroll
      for (int r = 0; r < 4; ++r) acc[m][n][r] = 0.f;

  for (int kt = 0; kt < kE; kt += 64) {
    #pragma unroll
    for (int i = 0; i < 4; ++i) {
      const int slot = w * 4 + i;
      const int row = slot * 8 + srow;
      const int sc = sch ^ srow;
      __builtin_amdgcn_global_load_lds(
          (gvoid_t*)(A + (size_t)(m0 + row) * kE + kt + 8 * sc),
          (lvoid_t*)(As + slot * 512), 16, 0, 0);
      __builtin_amdgcn_global_load_lds(
          (gvoid_t*)(BT + (size_t)(n0 + row) * kE + kt + 8 * sc),
          (lvoid_t*)(Bs + slot * 512), 16, 0, 0);
    }
    __syncthreads();
    #pragma unroll
    for (int kk = 0; kk < 2; ++kk) {
      bf16x8 af[4], bfr[4];
      #pragma unroll
      for (int m = 0; m < 4; ++m)
        af[m] = *(const bf16x8*)(As + (wr * 64 + m * 16 + lr) * 64 + (((4 * kk + g) ^ swz) << 3));
      #pragma unroll
      for (int n = 0; n < 4; ++n)
        bfr[n] = *(const bf16x8*)(Bs + (wc * 64 + n * 16 + lr) * 64 + (((4 * kk + g) ^ swz) << 3));
      __builtin_amdgcn_s_setprio(1);
      #pragma unroll
      for (int m = 0; m < 4; ++m)
        #pragma unroll
        for (int n = 0; n < 4; ++n)
          acc[m][n] = __builtin_amdgcn_mfma_f32_16x16x32_bf16(af[m], bfr[n], acc[m][n], 0, 0, 0);
      __builtin_amdgcn_s_setprio(0);
    }
    __syncthreads();
  }

  short* C = (n0 < 1024) ? Kb : Qb;
  const float scale = (n0 < 1024) ? 1.0f : qs;
  const int crow = m0 + wr * 64, ccol = (n0 & 1023) + wc * 64;
  #pragma unroll
  for (int m = 0; m < 4; ++m)
    #pragma unroll
    for (int n = 0; n < 4; ++n)
      #pragma unroll
      for (int r = 0; r < 4; ++r)
        C[(size_t)(crow + m * 16 + 4 * g + r) * kE + ccol + n * 16 + lr] =
            bfc(acc[m][n][r] * scale);
}

// ---------------- bf16 GEMM (m97 recipe): C = A @ BT^T + bias (f32 out) ----------------
__global__ __launch_bounds__(256)
void gemm_bt(const short* __restrict__ A, const short* __restrict__ BT,
             float* __restrict__ C, const float* __restrict__ bias,
             int M, int N, int K) {
  __shared__ short As[128 * 64];
  __shared__ short Bs[128 * 64];
  const int tid = threadIdx.x;
  const int w = tid >> 6, lane = tid & 63;
  const int g = lane >> 4, lr = lane & 15;
  const int bid = blockIdx.x;
  const int id = (bid & 7) * 64 + (bid >> 3);   // 512 % 8 == 0
  const int n0 = (id & 7) * 128, m0 = (id >> 3) * 128;
  const int wr = w >> 1, wc = w & 1;
  const int srow = lane >> 3, sch = lane & 7;
  const int swz = lr & 7;

  f32x4 acc[4][4];
  #pragma unroll
  for (int m = 0; m < 4; ++m)
    #pragma unroll
    for (int n = 0; n < 4; ++n)
      #pragma unroll
      for (int r = 0; r < 4; ++r) acc[m][n][r] = 0.f;

  for (int kt = 0; kt < K; kt += 64) {
    #pragma unroll
    for (int i = 0; i < 4; ++i) {
      const int slot = w * 4 + i;
      const int row = slot * 8 + srow;
      const int sc = sch ^ srow;
      __builtin_amdgcn_global_load_lds(
          (gvoid_t*)(A + (size_t)(m0 + row) * K + kt + 8 * sc),
          (lvoid_t*)(As + slot * 512), 16, 0, 0);
      __builtin_amdgcn_global_load_lds(
          (gvoid_t*)(BT + (size_t)(n0 + row) * K + kt + 8 * sc),
          (lvoid_t*)(Bs + slot * 512), 16, 0, 0);
    }
    __syncthreads();
    #pragma unroll
    for (int kk = 0; kk < 2; ++kk) {
      bf16x8 af[4], bfr[4];
      #pragma unroll
      for (int m = 0; m < 4; ++m)
        af[m] = *(const bf16x8*)(As + (wr * 64 + m * 16 + lr) * 64 + (((4 * kk + g) ^ swz) << 3));
      #pragma unroll
      for (int n = 0; n < 4; ++n)
        bfr[n] = *(const bf16x8*)(Bs + (wc * 64 + n * 16 + lr) * 64 + (((4 * kk + g) ^ swz) << 3));
      __builtin_amdgcn_s_setprio(1);
      #pragma unroll
      for (int m = 0; m < 4; ++m)
        #pragma unroll
        for (int n = 0; n < 4; ++n)
          acc[m][n] = __builtin_amdgcn_mfma_f32_16x16x32_bf16(af[m], bfr[n], acc[m][n], 0, 0, 0);
      __builtin_amdgcn_s_setprio(0);
    }
    __syncthreads();
  }

  const int crow = m0 + wr * 64, ccol = n0 + wc * 64;
  float bv[4];
  #pragma unroll
  for (int n = 0; n < 4; ++n) bv[n] = bias[ccol + n * 16 + lr];
  #pragma unroll
  for (int m = 0; m < 4; ++m)
    #pragma unroll
    for (int n = 0; n < 4; ++n)
      #pragma unroll
      for (int r = 0; r < 4; ++r)
        C[(size_t)(crow + m * 16 + 4 * g + r) * N + ccol + n * 16 + lr] =
            acc[m][n][r] + bv[n];
}

// ---------------- flash attention; V == K (faithful to reference bug) ----------------
// 32x32 swapped structure; R5-proven deferred-max online softmax (THR=8),
// f32 lsum + shfl(32) reduce. P -> PV B-frags in-register via cvt_pk +
// permlane32_swap (T12). Staging: Kt [kv][s] and Vt [s][kv] (from
// pre-transposed KT) via coalesced global_load_lds, double-buffered,
// XOR-chunk-swizzled via pre-swizzled source, one barrier per tile.
// Epilogue transpose uses a DEDICATED Ot array (stride 68) - no overlay.
__global__ __launch_bounds__(256, 3)
void attn_kernel(const short* Qb, const short* __restrict__ Kb,
                 const short* __restrict__ KT, short* AO) {
  __shared__ short Kt[2][64 * 64];   // 16 KB
  __shared__ short Vt[2][64 * 64];   // 16 KB
  __shared__ short Ot[4][32 * 68];   // 17 KB (epilogue transpose, per wave)

  const int tid = threadIdx.x;
  const int w = tid >> 6, lane = tid & 63;
  const int l31 = lane & 31, hi = lane >> 5;
  const int swz = l31 & 7;
  const int bid = blockIdx.x;
  const int id = (bid & 7) * 128 + (bid >> 3);  // XCD swizzle (1024 % 8 == 0)
  const int q0 = (id & 15) * 128;
  const int bh = id >> 4;                       // b*16 + h
  const size_t base = (size_t)(bh >> 4) * kT * kE + (size_t)(bh & 15) * kS;
  const short* Kbh = Kb + base;
  const short* KTbh = KT + (size_t)bh * 64 * kT;

  const int srow_lo = lane >> 3, sch = lane & 7;

  // ---- prologue: issue tile-0 staging ----
  #pragma unroll
  for (int i = 0; i < 2; ++i) {
    const int slot = w * 2 + i, row = slot * 8 + srow_lo;
    const int sc = sch ^ (row & 7);
    __builtin_amdgcn_global_load_lds(
        (gvoid_t*)(Kbh + (size_t)row * kE + 8 * sc),
        (lvoid_t*)(&Kt[0][0] + slot * 512), 16, 0, 0);
    __builtin_amdgcn_global_load_lds(
        (gvoid_t*)(KTbh + (size_t)row * kT + 8 * sc),
        (lvoid_t*)(&Vt[0][0] + slot * 512), 16, 0, 0);
  }

  bf16x8 qB[4];
  #pragma unroll
  for (int ks = 0; ks < 4; ++ks)
    qB[ks] = *(const bf16x8*)(Qb + base +
        (size_t)(q0 + w * 32 + l31) * kE + ks * 16 + hi * 8);

  f32x16 oacc[2];
  #pragma unroll
  for (int r = 0; r < 16; ++r) { oacc[0][r] = 0.f; oacc[1][r] = 0.f; }
  float lsum = 0.f, mrow = -1e30f;

  for (int t = 0; t < 32; ++t) {
    __syncthreads();   // tile-t staging drained; prev-tile reads complete

    // ---- issue tile t+1 staging (hidden under this tile's compute) ----
    if (t < 31) {
      const short* kbt = Kbh + (size_t)(t + 1) * 64 * kE;
      const short* vtt = KTbh + (size_t)(t + 1) * 64;
      short* KtN = &Kt[(t + 1) & 1][0];
      short* VtN = &Vt[(t + 1) & 1][0];
      #pragma unroll
      for (int i = 0; i < 2; ++i) {
        const int slot = w * 2 + i, row = slot * 8 + srow_lo;
        const int sc = sch ^ (row & 7);
        __builtin_amdgcn_global_load_lds(
            (gvoid_t*)(kbt + (size_t)row * kE + 8 * sc),
            (lvoid_t*)(KtN + slot * 512), 16, 0, 0);
        __builtin_amdgcn_global_load_lds(
            (gvoid_t*)(vtt + (size_t)row * kT + 8 * sc),
            (lvoid_t*)(VtN + slot * 512), 16, 0, 0);
      }
    }

    const short* KtC = &Kt[t & 1][0];
    const short* VtC = &Vt[t & 1][0];

    // ---- S^T = K Q^T (32x32x16) ----
    f32x16 sacc[2];
    #pragma unroll
    for (int r = 0; r < 16; ++r) { sacc[0][r] = 0.f; sacc[1][r] = 0.f; }
    #pragma unroll
    for (int ks = 0; ks < 4; ++ks) {
      const int pc = ((2 * ks + hi) ^ swz) << 3;
      bf16x8 kf0 = *(const bf16x8*)(KtC + (l31)      * 64 + pc);
      bf16x8 kf1 = *(const bf16x8*)(KtC + (32 + l31) * 64 + pc);
      __builtin_amdgcn_s_setprio(1);
      sacc[0] = __builtin_amdgcn_mfma_f32_32x32x16_bf16(kf0, qB[ks], sacc[0], 0, 0, 0);
      sacc[1] = __builtin_amdgcn_mfma_f32_32x32x16_bf16(kf1, qB[ks], sacc[1], 0, 0, 0);
      __builtin_amdgcn_s_setprio(0);
    }

    // ---- online softmax, deferred rescale (THR=8); lane owns q-col l31 ----
    float tmax = sacc[0][0];
    #pragma unroll
    for (int kvf = 0; kvf < 2; ++kvf)
      #pragma unroll
      for (int r = 0; r < 16; ++r)
        if (kvf | r) tmax = fmaxf(tmax, sacc[kvf][r]);
    tmax = fmaxf(tmax, __shfl_xor(tmax, 32));
    if (!__all(tmax <= mrow + 8.f)) {
      const float mn = fmaxf(mrow, tmax);
      const float a = fexp2(mrow - mn);
      mrow = mn;
      lsum *= a;
      #pragma unroll
      for (int sf = 0; sf < 2; ++sf)
        #pragma unroll
        for (int r = 0; r < 16; ++r) oacc[sf][r] *= a;
    }

    // ---- P = exp2(S^T - m); build PV B-frags in-register (T12) ----
    union { unsigned u[4]; bf16x8 v; } pf[4];
    #pragma unroll
    for (int kvf = 0; kvf < 2; ++kvf) {
      float pe[16];
      #pragma unroll
      for (int r = 0; r < 16; ++r) {
        pe[r] = fexp2(sacc[kvf][r] - mrow);
        lsum += pe[r];
      }
      #pragma unroll
      for (int sub = 0; sub < 2; ++sub) {
        unsigned a0 = cvt_pk(pe[8 * sub + 0], pe[8 * sub + 1]);
        unsigned b0 = cvt_pk(pe[8 * sub + 4], pe[8 * sub + 5]);
        plane_swap(a0, b0);
        unsigned a1 = cvt_pk(pe[8 * sub + 2], pe[8 * sub + 3]);
        unsigned b1 = cvt_pk(pe[8 * sub + 6], pe[8 * sub + 7]);
        plane_swap(a1, b1);
        pf[2 * kvf + sub].u[0] = a0;
        pf[2 * kvf + sub].u[1] = a1;
        pf[2 * kvf + sub].u[2] = b0;
        pf[2 * kvf + sub].u[3] = b1;
      }
    }

    // ---- O^T += V^T P^T ----
    #pragma unroll
    for (int ks = 0; ks < 4; ++ks) {
      const int pc = ((2 * ks + hi) ^ swz) << 3;
      bf16x8 vf0 = *(const bf16x8*)(VtC + (l31)      * 64 + pc);
      bf16x8 vf1 = *(const bf16x8*)(VtC + (32 + l31) * 64 + pc);
      __builtin_amdgcn_s_setprio(1);
      oacc[0] = __builtin_amdgcn_mfma_f32_32x32x16_bf16(vf0, pf[ks].v, oacc[0], 0, 0, 0);
      oacc[1] = __builtin_amdgcn_mfma_f32_32x32x16_bf16(vf1, pf[ks].v, oacc[1], 0, 0, 0);
      __builtin_amdgcn_s_setprio(0);
    }
  }

  __syncthreads();

  // ---- epilogue: O = O^T / l via dedicated Ot (stride 68), coalesced stores ----
  const float ltot = lsum + __shfl_xor(lsum, 32);
  const float inv = 1.f / ltot;
  short* OtW = &Ot[w][0];   // 32 q x 68 per wave
  #pragma unroll
  for (int sf = 0; sf < 2; ++sf)
    #pragma unroll
    for (int c = 0; c < 4; ++c) {
      u32x2 e;
      e[0] = cvt_pk(oacc[sf][4 * c + 0] * inv, oacc[sf][4 * c + 1] * inv);
      e[1] = cvt_pk(oacc[sf][4 * c + 2] * inv, oacc[sf][4 * c + 3] * inv);
      *(u32x2*)(OtW + l31 * 68 + sf * 32 + 8 * c + 4 * hi) = e;
    }
  __builtin_amdgcn_s_barrier();
  #pragma unroll
  for (int i = 0; i < 8; ++i) {
    const int row = i * 4 + (lane >> 4);
    u32x2 v = *(const u32x2*)(OtW + row * 68 + (lane & 15) * 4);
    *(u32x2*)(AO + base + (size_t)(q0 + w * 32 + row) * kE + (lane & 15) * 4) = v;
  }
}

// ---------------- launch ----------------
extern "C" void kernel_launch(void* const* d_in, const int* in_sizes, int n_in,
                              void* d_out, int out_size, void* d_ws, size_t ws_size,
                              hipStream_t stream) {
  const float* x  = (const float*)d_in[0];
  const float* Wk = (const float*)d_in[1];
  const float* Wq = (const float*)d_in[2];
  const float* Wo = (const float*)d_in[3];
  const float* bo = (const float*)d_in[4];
  float* out = (float*)d_out;

  const size_t nXE = (size_t)kRows * kE;  // 8388608
  const size_t nW  = (size_t)kE * kE;     // 1048576

  short* Xb   = (short*)d_ws;
  short* Kb   = Xb   + nXE;
  short* Qb   = Kb   + nXE;
  short* WkqT = Qb   + nXE;          // [2048][1024]
  short* WoT  = WkqT + 2 * nW;
  short* KTb  = Xb;   // reuse: x-bf16 dead after projections
  short* AO   = Qb;   // reuse: each block reads its own Qb region before writing it

  cvt_bf16<<<dim3(nXE / (4 * 256)), 256, 0, stream>>>(x, Xb);
  transpose_cvt<<<dim3(32, 32), 256, 0, stream>>>(Wk, WkqT);
  transpose_cvt<<<dim3(32, 32), 256, 0, stream>>>(Wq, WkqT + nW);
  transpose_cvt<<<dim3(32, 32), 256, 0, stream>>>(Wo, WoT);

  // Fused K(=V) and Q projections; Q scaled by E^-0.5 * log2(e)
  gemm_kq<<<dim3(1024), 256, 0, stream>>>(
      Xb, WkqT, Kb, Qb, 0.03125f * 1.44269504f);

  // V^T = K^T per (b,h): [bh][s][t]  (overwrites Xb)
  transv<<<dim3(kT / 64, kB * kH), 256, 0, stream>>>(Kb, KTb);

  attn_kernel<<<dim3(1024), 256, 0, stream>>>(Qb, Kb, KTb, AO);

  gemm_bt<<<dim3(512), 256, 0, stream>>>(
      AO, WoT, out, bo, kRows, kE, kE);
}

// Round 9
// 177.405 us; speedup vs baseline: 1.3753x; 1.1005x over previous
//
#include <hip/hip_runtime.h>
#include <hip/hip_bf16.h>
#include <stdint.h>

// Problem constants
static constexpr int kB = 4;
static constexpr int kT = 2048;
static constexpr int kE = 1024;
static constexpr int kH = 16;
static constexpr int kS = 64;          // head dim
static constexpr int kRows = kB * kT;  // 8192

typedef __attribute__((ext_vector_type(4)))  float    f32x4;
typedef __attribute__((ext_vector_type(16))) float    f32x16;
typedef __attribute__((ext_vector_type(4)))  float    float4v;
typedef __attribute__((ext_vector_type(8)))  __bf16   bf16x8;
typedef __attribute__((ext_vector_type(8)))  short    short8v;
typedef __attribute__((ext_vector_type(4)))  short    short4v;
typedef __attribute__((ext_vector_type(2)))  unsigned u32x2;

typedef const __attribute__((address_space(1))) void gvoid_t;
typedef __attribute__((address_space(3))) void lvoid_t;

__device__ __forceinline__ short f2bf(float f) {
  union { float f; unsigned u; } c; c.f = f;
  unsigned r = (c.u + 0x7FFFu + ((c.u >> 16) & 1u)) >> 16;
  return (short)(r & 0xFFFFu);
}

__device__ __forceinline__ short bfc(float f) {
  union { __bf16 b; short s; } u; u.b = (__bf16)f; return u.s;
}

// v_cvt_pk_bf16_f32: D[15:0]=bf16(lo), D[31:16]=bf16(hi).
__device__ __forceinline__ unsigned cvt_pk(float lo, float hi) {
  unsigned r;
  asm("v_cvt_pk_bf16_f32 %0, %1, %2" : "=v"(r) : "v"(lo), "v"(hi));
  return r;
}

// v_permlane32_swap_b32: a' = [a.lo, b.lo], b' = [a.hi, b.hi]
__device__ __forceinline__ void plane_swap(unsigned& a, unsigned& b) {
  asm("v_permlane32_swap_b32 %0, %1" : "+v"(a), "+v"(b));
}

#if __has_builtin(__builtin_amdgcn_exp2f)
__device__ __forceinline__ float fexp2(float x) { return __builtin_amdgcn_exp2f(x); }
#else
__device__ __forceinline__ float fexp2(float x) { return exp2f(x); }
#endif

// ---------------- convert f32 -> bf16 (vectorized) ----------------
__global__ void cvt_bf16(const float* __restrict__ in, short* __restrict__ out) {
  size_t i = (size_t)(blockIdx.x * blockDim.x + threadIdx.x) * 4;
  float4v x = *(const float4v*)(in + i);
  short4v o;
  o[0] = f2bf(x[0]); o[1] = f2bf(x[1]); o[2] = f2bf(x[2]); o[3] = f2bf(x[3]);
  *(short4v*)(out + i) = o;
}

// ---------------- transpose + convert: W[k][n] f32 -> WT[n][k] bf16 ----------------
__global__ void transpose_cvt(const float* __restrict__ W, short* __restrict__ WT) {
  __shared__ float tile[32][33];
  const int tx = threadIdx.x & 31, ty = threadIdx.x >> 5;  // 32 x 8
  const int c = blockIdx.x * 32, r = blockIdx.y * 32;
  #pragma unroll
  for (int i = ty; i < 32; i += 8)
    tile[i][tx] = W[(size_t)(r + i) * kE + c + tx];
  __syncthreads();
  #pragma unroll
  for (int i = ty; i < 32; i += 8)
    WT[(size_t)(c + i) * kE + r + tx] = f2bf(tile[tx][i]);
}

// ---------------- V transpose: Kb[b][t][h][s] -> KT[(b*16+h)][s][t] (bf16) ----------------
__global__ __launch_bounds__(256)
void transv(const short* __restrict__ Kb, short* __restrict__ KT) {
  __shared__ short tile[64][72];
  const int tid = threadIdx.x;
  const int bh = blockIdx.y;               // b*16 + h
  const int t0 = blockIdx.x * 64;
  const size_t base = (size_t)(bh >> 4) * kT * kE + (size_t)(bh & 15) * kS;
  #pragma unroll
  for (int i = 0; i < 2; ++i) {
    const int row = i * 32 + (tid >> 3), c = (tid & 7) * 8;
    *(short8v*)&tile[row][c] =
        *(const short8v*)(Kb + base + (size_t)(t0 + row) * kE + c);
  }
  __syncthreads();
  #pragma unroll
  for (int i = 0; i < 2; ++i) {
    const int s = i * 32 + (tid >> 3), c = (tid & 7) * 8;
    short8v o;
    #pragma unroll
    for (int j = 0; j < 8; ++j) o[j] = tile[c + j][s];
    *(short8v*)(KT + ((size_t)bh * 64 + s) * kT + t0 + c) = o;
  }
}

// ---------------- fused K+Q projection GEMM ----------------
// A[8192,1024] bf16, WkqT[2048][1024] bf16 (rows 0-1023 = Wk^T, 1024-2047 = Wq^T).
// C: n<1024 -> Kb (scale 1), else Qb (scale qs). 1024 blocks, XCD-swizzled.
__global__ __launch_bounds__(256)
void gemm_kq(const short* __restrict__ A, const short* __restrict__ BT,
             short* __restrict__ Kb, short* __restrict__ Qb, float qs) {
  __shared__ short As[128 * 64];
  __shared__ short Bs[128 * 64];
  const int tid = threadIdx.x;
  const int w = tid >> 6, lane = tid & 63;
  const int g = lane >> 4, lr = lane & 15;
  const int bid = blockIdx.x;
  const int id = (bid & 7) * 128 + (bid >> 3);   // 1024 % 8 == 0, bijective
  const int n0 = (id & 15) * 128, m0 = (id >> 4) * 128;
  const int wr = w >> 1, wc = w & 1;
  const int srow = lane >> 3, sch = lane & 7;
  const int swz = lr & 7;

  f32x4 acc[4][4];
  #pragma unroll
  for (int m = 0; m < 4; ++m)
    #pragma unroll
    for (int n = 0; n < 4; ++n)
      #pragma unroll
      for (int r = 0; r < 4; ++r) acc[m][n][r] = 0.f;

  for (int kt = 0; kt < kE; kt += 64) {
    #pragma unroll
    for (int i = 0; i < 4; ++i) {
      const int slot = w * 4 + i;
      const int row = slot * 8 + srow;
      const int sc = sch ^ srow;
      __builtin_amdgcn_global_load_lds(
          (gvoid_t*)(A + (size_t)(m0 + row) * kE + kt + 8 * sc),
          (lvoid_t*)(As + slot * 512), 16, 0, 0);
      __builtin_amdgcn_global_load_lds(
          (gvoid_t*)(BT + (size_t)(n0 + row) * kE + kt + 8 * sc),
          (lvoid_t*)(Bs + slot * 512), 16, 0, 0);
    }
    __syncthreads();
    #pragma unroll
    for (int kk = 0; kk < 2; ++kk) {
      bf16x8 af[4], bfr[4];
      #pragma unroll
      for (int m = 0; m < 4; ++m)
        af[m] = *(const bf16x8*)(As + (wr * 64 + m * 16 + lr) * 64 + (((4 * kk + g) ^ swz) << 3));
      #pragma unroll
      for (int n = 0; n < 4; ++n)
        bfr[n] = *(const bf16x8*)(Bs + (wc * 64 + n * 16 + lr) * 64 + (((4 * kk + g) ^ swz) << 3));
      __builtin_amdgcn_s_setprio(1);
      #pragma unroll
      for (int m = 0; m < 4; ++m)
        #pragma unroll
        for (int n = 0; n < 4; ++n)
          acc[m][n] = __builtin_amdgcn_mfma_f32_16x16x32_bf16(af[m], bfr[n], acc[m][n], 0, 0, 0);
      __builtin_amdgcn_s_setprio(0);
    }
    __syncthreads();
  }

  short* C = (n0 < 1024) ? Kb : Qb;
  const float scale = (n0 < 1024) ? 1.0f : qs;
  const int crow = m0 + wr * 64, ccol = (n0 & 1023) + wc * 64;
  #pragma unroll
  for (int m = 0; m < 4; ++m)
    #pragma unroll
    for (int n = 0; n < 4; ++n)
      #pragma unroll
      for (int r = 0; r < 4; ++r)
        C[(size_t)(crow + m * 16 + 4 * g + r) * kE + ccol + n * 16 + lr] =
            bfc(acc[m][n][r] * scale);
}

// ---------------- bf16 GEMM (m97 recipe): C = A @ BT^T + bias (f32 out) ----------------
__global__ __launch_bounds__(256)
void gemm_bt(const short* __restrict__ A, const short* __restrict__ BT,
             float* __restrict__ C, const float* __restrict__ bias,
             int M, int N, int K) {
  __shared__ short As[128 * 64];
  __shared__ short Bs[128 * 64];
  const int tid = threadIdx.x;
  const int w = tid >> 6, lane = tid & 63;
  const int g = lane >> 4, lr = lane & 15;
  const int bid = blockIdx.x;
  const int id = (bid & 7) * 64 + (bid >> 3);   // 512 % 8 == 0
  const int n0 = (id & 7) * 128, m0 = (id >> 3) * 128;
  const int wr = w >> 1, wc = w & 1;
  const int srow = lane >> 3, sch = lane & 7;
  const int swz = lr & 7;

  f32x4 acc[4][4];
  #pragma unroll
  for (int m = 0; m < 4; ++m)
    #pragma unroll
    for (int n = 0; n < 4; ++n)
      #pragma unroll
      for (int r = 0; r < 4; ++r) acc[m][n][r] = 0.f;

  for (int kt = 0; kt < K; kt += 64) {
    #pragma unroll
    for (int i = 0; i < 4; ++i) {
      const int slot = w * 4 + i;
      const int row = slot * 8 + srow;
      const int sc = sch ^ srow;
      __builtin_amdgcn_global_load_lds(
          (gvoid_t*)(A + (size_t)(m0 + row) * K + kt + 8 * sc),
          (lvoid_t*)(As + slot * 512), 16, 0, 0);
      __builtin_amdgcn_global_load_lds(
          (gvoid_t*)(BT + (size_t)(n0 + row) * K + kt + 8 * sc),
          (lvoid_t*)(Bs + slot * 512), 16, 0, 0);
    }
    __syncthreads();
    #pragma unroll
    for (int kk = 0; kk < 2; ++kk) {
      bf16x8 af[4], bfr[4];
      #pragma unroll
      for (int m = 0; m < 4; ++m)
        af[m] = *(const bf16x8*)(As + (wr * 64 + m * 16 + lr) * 64 + (((4 * kk + g) ^ swz) << 3));
      #pragma unroll
      for (int n = 0; n < 4; ++n)
        bfr[n] = *(const bf16x8*)(Bs + (wc * 64 + n * 16 + lr) * 64 + (((4 * kk + g) ^ swz) << 3));
      __builtin_amdgcn_s_setprio(1);
      #pragma unroll
      for (int m = 0; m < 4; ++m)
        #pragma unroll
        for (int n = 0; n < 4; ++n)
          acc[m][n] = __builtin_amdgcn_mfma_f32_16x16x32_bf16(af[m], bfr[n], acc[m][n], 0, 0, 0);
      __builtin_amdgcn_s_setprio(0);
    }
    __syncthreads();
  }

  const int crow = m0 + wr * 64, ccol = n0 + wc * 64;
  float bv[4];
  #pragma unroll
  for (int n = 0; n < 4; ++n) bv[n] = bias[ccol + n * 16 + lr];
  #pragma unroll
  for (int m = 0; m < 4; ++m)
    #pragma unroll
    for (int n = 0; n < 4; ++n)
      #pragma unroll
      for (int r = 0; r < 4; ++r)
        C[(size_t)(crow + m * 16 + 4 * g + r) * N + ccol + n * 16 + lr] =
            acc[m][n][r] + bv[n];
}

// ---------------- flash attention; V == K (faithful to reference bug) ----------------
// 32x32 swapped structure. STATIC softmax m=0 (shift-invariant, scores
// |s| < ~2 here). Q pre-scaled by E^-0.5 * log2(e) so P = exp2(s').
// l computed the R5/R7-PROVEN way: f32 lsum of pe + shfl_xor(32) pair-sum
// (the R6/R8 ones-MFMA l path failed on HW twice - do not reintroduce).
// P -> PV B-frags in-register via cvt_pk + permlane32_swap (T12).
// Staging: Kt [kv][s] / Vt [s][kv] via coalesced global_load_lds,
// double-buffered, XOR-chunk-swizzled source, one barrier per tile.
// Epilogue reuses staging pool (4 waves x 32 x 68 = 8704 <= 16384 shorts).
__global__ __launch_bounds__(256, 4)
void attn_kernel(const short* Qb, const short* __restrict__ Kb,
                 const short* __restrict__ KT, short* AO) {
  __shared__ short SM[16384];   // 32 KB: Kt[2] @ 0/4096, Vt[2] @ 8192/12288

  const int tid = threadIdx.x;
  const int w = tid >> 6, lane = tid & 63;
  const int l31 = lane & 31, hi = lane >> 5;
  const int swz = l31 & 7;
  const int bid = blockIdx.x;
  const int id = (bid & 7) * 128 + (bid >> 3);  // XCD swizzle (1024 % 8 == 0)
  const int q0 = (id & 15) * 128;
  const int bh = id >> 4;                       // b*16 + h
  const size_t base = (size_t)(bh >> 4) * kT * kE + (size_t)(bh & 15) * kS;
  const short* Kbh = Kb + base;
  const short* KTbh = KT + (size_t)bh * 64 * kT;

  const int srow_lo = lane >> 3, sch = lane & 7;

  // ---- prologue: issue tile-0 staging ----
  #pragma unroll
  for (int i = 0; i < 2; ++i) {
    const int slot = w * 2 + i, row = slot * 8 + srow_lo;
    const int sc = sch ^ (row & 7);
    __builtin_amdgcn_global_load_lds(
        (gvoid_t*)(Kbh + (size_t)row * kE + 8 * sc),
        (lvoid_t*)(SM + slot * 512), 16, 0, 0);
    __builtin_amdgcn_global_load_lds(
        (gvoid_t*)(KTbh + (size_t)row * kT + 8 * sc),
        (lvoid_t*)(SM + 8192 + slot * 512), 16, 0, 0);
  }

  bf16x8 qB[4];
  #pragma unroll
  for (int ks = 0; ks < 4; ++ks)
    qB[ks] = *(const bf16x8*)(Qb + base +
        (size_t)(q0 + w * 32 + l31) * kE + ks * 16 + hi * 8);

  f32x16 oacc[2];
  #pragma unroll
  for (int r = 0; r < 16; ++r) { oacc[0][r] = 0.f; oacc[1][r] = 0.f; }
  float lsum = 0.f;

  for (int t = 0; t < 32; ++t) {
    __syncthreads();   // tile-t staging drained; prev-tile reads complete

    // ---- issue tile t+1 staging (hidden under this tile's compute) ----
    if (t < 31) {
      const short* kbt = Kbh + (size_t)(t + 1) * 64 * kE;
      const short* vtt = KTbh + (size_t)(t + 1) * 64;
      short* KtN = SM + ((t + 1) & 1) * 4096;
      short* VtN = SM + 8192 + ((t + 1) & 1) * 4096;
      #pragma unroll
      for (int i = 0; i < 2; ++i) {
        const int slot = w * 2 + i, row = slot * 8 + srow_lo;
        const int sc = sch ^ (row & 7);
        __builtin_amdgcn_global_load_lds(
            (gvoid_t*)(kbt + (size_t)row * kE + 8 * sc),
            (lvoid_t*)(KtN + slot * 512), 16, 0, 0);
        __builtin_amdgcn_global_load_lds(
            (gvoid_t*)(vtt + (size_t)row * kT + 8 * sc),
            (lvoid_t*)(VtN + slot * 512), 16, 0, 0);
      }
    }

    const short* KtC = SM + (t & 1) * 4096;
    const short* VtC = SM + 8192 + (t & 1) * 4096;

    // ---- S^T = K Q^T (32x32x16) ----
    f32x16 sacc[2];
    #pragma unroll
    for (int r = 0; r < 16; ++r) { sacc[0][r] = 0.f; sacc[1][r] = 0.f; }
    #pragma unroll
    for (int ks = 0; ks < 4; ++ks) {
      const int pc = ((2 * ks + hi) ^ swz) << 3;
      bf16x8 kf0 = *(const bf16x8*)(KtC + (l31)      * 64 + pc);
      bf16x8 kf1 = *(const bf16x8*)(KtC + (32 + l31) * 64 + pc);
      __builtin_amdgcn_s_setprio(1);
      sacc[0] = __builtin_amdgcn_mfma_f32_32x32x16_bf16(kf0, qB[ks], sacc[0], 0, 0, 0);
      sacc[1] = __builtin_amdgcn_mfma_f32_32x32x16_bf16(kf1, qB[ks], sacc[1], 0, 0, 0);
      __builtin_amdgcn_s_setprio(0);
    }

    // ---- P = exp2(S^T); f32 lsum; build PV B-frags in-register (T12) ----
    union { unsigned u[4]; bf16x8 v; } pf[4];
    #pragma unroll
    for (int kvf = 0; kvf < 2; ++kvf) {
      float pe[16];
      #pragma unroll
      for (int r = 0; r < 16; ++r) {
        pe[r] = fexp2(sacc[kvf][r]);
        lsum += pe[r];
      }
      #pragma unroll
      for (int sub = 0; sub < 2; ++sub) {
        unsigned a0 = cvt_pk(pe[8 * sub + 0], pe[8 * sub + 1]);
        unsigned b0 = cvt_pk(pe[8 * sub + 4], pe[8 * sub + 5]);
        plane_swap(a0, b0);
        unsigned a1 = cvt_pk(pe[8 * sub + 2], pe[8 * sub + 3]);
        unsigned b1 = cvt_pk(pe[8 * sub + 6], pe[8 * sub + 7]);
        plane_swap(a1, b1);
        pf[2 * kvf + sub].u[0] = a0;
        pf[2 * kvf + sub].u[1] = a1;
        pf[2 * kvf + sub].u[2] = b0;
        pf[2 * kvf + sub].u[3] = b1;
      }
    }

    // ---- O^T += V^T P^T ----
    #pragma unroll
    for (int ks = 0; ks < 4; ++ks) {
      const int pc = ((2 * ks + hi) ^ swz) << 3;
      bf16x8 vf0 = *(const bf16x8*)(VtC + (l31)      * 64 + pc);
      bf16x8 vf1 = *(const bf16x8*)(VtC + (32 + l31) * 64 + pc);
      __builtin_amdgcn_s_setprio(1);
      oacc[0] = __builtin_amdgcn_mfma_f32_32x32x16_bf16(vf0, pf[ks].v, oacc[0], 0, 0, 0);
      oacc[1] = __builtin_amdgcn_mfma_f32_32x32x16_bf16(vf1, pf[ks].v, oacc[1], 0, 0, 0);
      __builtin_amdgcn_s_setprio(0);
    }
  }

  __syncthreads();   // all PV reads done before reusing the pool for O transpose

  // ---- epilogue: O = O^T / l via pool-reuse Ot (stride 68), coalesced stores ----
  const float ltot = lsum + __shfl_xor(lsum, 32);  // lane pair (q=l31) holds halves
  const float inv = 1.f / ltot;
  short* OtW = SM + w * 2176;        // 32 q x 68 per wave; 4*2176=8704 <= 16384
  #pragma unroll
  for (int sf = 0; sf < 2; ++sf)
    #pragma unroll
    for (int c = 0; c < 4; ++c) {
      u32x2 e;
      e[0] = cvt_pk(oacc[sf][4 * c + 0] * inv, oacc[sf][4 * c + 1] * inv);
      e[1] = cvt_pk(oacc[sf][4 * c + 2] * inv, oacc[sf][4 * c + 3] * inv);
      *(u32x2*)(OtW + l31 * 68 + sf * 32 + 8 * c + 4 * hi) = e;
    }
  __builtin_amdgcn_s_barrier();
  #pragma unroll
  for (int i = 0; i < 8; ++i) {
    const int row = i * 4 + (lane >> 4);
    u32x2 v = *(const u32x2*)(OtW + row * 68 + (lane & 15) * 4);
    *(u32x2*)(AO + base + (size_t)(q0 + w * 32 + row) * kE + (lane & 15) * 4) = v;
  }
}

// ---------------- launch ----------------
extern "C" void kernel_launch(void* const* d_in, const int* in_sizes, int n_in,
                              void* d_out, int out_size, void* d_ws, size_t ws_size,
                              hipStream_t stream) {
  const float* x  = (const float*)d_in[0];
  const float* Wk = (const float*)d_in[1];
  const float* Wq = (const float*)d_in[2];
  const float* Wo = (const float*)d_in[3];
  const float* bo = (const float*)d_in[4];
  float* out = (float*)d_out;

  const size_t nXE = (size_t)kRows * kE;  // 8388608
  const size_t nW  = (size_t)kE * kE;     // 1048576

  short* Xb   = (short*)d_ws;
  short* Kb   = Xb   + nXE;
  short* Qb   = Kb   + nXE;
  short* WkqT = Qb   + nXE;          // [2048][1024]
  short* WoT  = WkqT + 2 * nW;
  short* KTb  = Xb;   // reuse: x-bf16 dead after projections
  short* AO   = Qb;   // reuse: each block reads its own Qb region before writing it

  cvt_bf16<<<dim3(nXE / (4 * 256)), 256, 0, stream>>>(x, Xb);
  transpose_cvt<<<dim3(32, 32), 256, 0, stream>>>(Wk, WkqT);
  transpose_cvt<<<dim3(32, 32), 256, 0, stream>>>(Wq, WkqT + nW);
  transpose_cvt<<<dim3(32, 32), 256, 0, stream>>>(Wo, WoT);

  // Fused K(=V) and Q projections; Q scaled by E^-0.5 * log2(e)
  gemm_kq<<<dim3(1024), 256, 0, stream>>>(
      Xb, WkqT, Kb, Qb, 0.03125f * 1.44269504f);

  // V^T = K^T per (b,h): [bh][s][t]  (overwrites Xb)
  transv<<<dim3(kT / 64, kB * kH), 256, 0, stream>>>(Kb, KTb);

  attn_kernel<<<dim3(1024), 256, 0, stream>>>(Qb, Kb, KTb, AO);

  gemm_bt<<<dim3(512), 256, 0, stream>>>(
      AO, WoT, out, bo, kRows, kE, kE);
}

// Round 10
// 172.503 us; speedup vs baseline: 1.4144x; 1.0284x over previous
//
#include <hip/hip_runtime.h>
#include <hip/hip_bf16.h>
#include <stdint.h>

// Problem constants
static constexpr int kB = 4;
static constexpr int kT = 2048;
static constexpr int kE = 1024;
static constexpr int kH = 16;
static constexpr int kS = 64;          // head dim
static constexpr int kRows = kB * kT;  // 8192

typedef __attribute__((ext_vector_type(4)))  float    f32x4;
typedef __attribute__((ext_vector_type(16))) float    f32x16;
typedef __attribute__((ext_vector_type(4)))  float    float4v;
typedef __attribute__((ext_vector_type(8)))  __bf16   bf16x8;
typedef __attribute__((ext_vector_type(8)))  short    short8v;
typedef __attribute__((ext_vector_type(4)))  short    short4v;
typedef __attribute__((ext_vector_type(2)))  unsigned u32x2;
typedef __attribute__((ext_vector_type(4)))  unsigned u32x4;

typedef const __attribute__((address_space(1))) void gvoid_t;
typedef __attribute__((address_space(3))) void lvoid_t;

__device__ __forceinline__ short f2bf(float f) {
  union { float f; unsigned u; } c; c.f = f;
  unsigned r = (c.u + 0x7FFFu + ((c.u >> 16) & 1u)) >> 16;
  return (short)(r & 0xFFFFu);
}

__device__ __forceinline__ short bfc(float f) {
  union { __bf16 b; short s; } u; u.b = (__bf16)f; return u.s;
}

// v_cvt_pk_bf16_f32: D[15:0]=bf16(lo), D[31:16]=bf16(hi).
__device__ __forceinline__ unsigned cvt_pk(float lo, float hi) {
  unsigned r;
  asm("v_cvt_pk_bf16_f32 %0, %1, %2" : "=v"(r) : "v"(lo), "v"(hi));
  return r;
}

// v_permlane32_swap_b32: a' = [a.lo, b.lo], b' = [a.hi, b.hi]
__device__ __forceinline__ void plane_swap(unsigned& a, unsigned& b) {
  asm("v_permlane32_swap_b32 %0, %1" : "+v"(a), "+v"(b));
}

#if __has_builtin(__builtin_amdgcn_exp2f)
__device__ __forceinline__ float fexp2(float x) { return __builtin_amdgcn_exp2f(x); }
#else
__device__ __forceinline__ float fexp2(float x) { return exp2f(x); }
#endif

// ---------------- fused prologue: x->bf16 + three W transposes ----------------
// blocks [0, 8192): convert x (1024 f32 each)
// blocks [8192, 11264): 32x32 transpose tiles; which = (bid-8192)>>10
__global__ __launch_bounds__(256)
void prep(const float* __restrict__ x, const float* __restrict__ Wk,
          const float* __restrict__ Wq, const float* __restrict__ Wo,
          short* __restrict__ Xb, short* __restrict__ WkqT,
          short* __restrict__ WoT) {
  const int bid = blockIdx.x;
  if (bid < 8192) {
    size_t i = ((size_t)bid * 256 + threadIdx.x) * 4;
    float4v v = *(const float4v*)(x + i);
    short4v o;
    o[0] = f2bf(v[0]); o[1] = f2bf(v[1]); o[2] = f2bf(v[2]); o[3] = f2bf(v[3]);
    *(short4v*)(Xb + i) = o;
    return;
  }
  __shared__ float tile[32][33];
  const int tb = bid - 8192;
  const int which = tb >> 10, t = tb & 1023;
  const float* W = (which == 0) ? Wk : ((which == 1) ? Wq : Wo);
  short* WT = (which == 0) ? WkqT : ((which == 1) ? (WkqT + kE * kE) : WoT);
  const int tx = threadIdx.x & 31, ty = threadIdx.x >> 5;  // 32 x 8
  const int c = (t & 31) * 32, r = (t >> 5) * 32;
  #pragma unroll
  for (int i = ty; i < 32; i += 8)
    tile[i][tx] = W[(size_t)(r + i) * kE + c + tx];
  __syncthreads();
  #pragma unroll
  for (int i = ty; i < 32; i += 8)
    WT[(size_t)(c + i) * kE + r + tx] = f2bf(tile[tx][i]);
}

// ---------------- fused K+Q projection GEMM (+ transposed K output) ----------------
// A[8192,1024] bf16, WkqT[2048][1024] bf16 (rows 0-1023 = Wk^T, 1024-2047 = Wq^T).
// n<1024 -> Kb (scale 1) AND transposed KT[(b*16+h)*64+s][t]; else Qb (scale qs).
// 1024 blocks, XCD-swizzled.
__global__ __launch_bounds__(256)
void gemm_kq(const short* __restrict__ A, const short* __restrict__ BT,
             short* __restrict__ Kb, short* __restrict__ Qb,
             short* __restrict__ KT, float qs) {
  __shared__ short SMp[16384];       // As @ 0 (16 KB), Bs @ 8192 (16 KB)
  short* As = SMp;
  short* Bs = SMp + 8192;
  const int tid = threadIdx.x;
  const int w = tid >> 6, lane = tid & 63;
  const int g = lane >> 4, lr = lane & 15;
  const int bid = blockIdx.x;
  const int id = (bid & 7) * 128 + (bid >> 3);   // 1024 % 8 == 0, bijective
  const int n0 = (id & 15) * 128, m0 = (id >> 4) * 128;
  const int wr = w >> 1, wc = w & 1;
  const int srow = lane >> 3, sch = lane & 7;
  const int swz = lr & 7;

  f32x4 acc[4][4];
  #pragma unroll
  for (int m = 0; m < 4; ++m)
    #pragma unroll
    for (int n = 0; n < 4; ++n)
      #pragma unroll
      for (int r = 0; r < 4; ++r) acc[m][n][r] = 0.f;

  for (int kt = 0; kt < kE; kt += 64) {
    #pragma unroll
    for (int i = 0; i < 4; ++i) {
      const int slot = w * 4 + i;
      const int row = slot * 8 + srow;
      const int sc = sch ^ srow;
      __builtin_amdgcn_global_load_lds(
          (gvoid_t*)(A + (size_t)(m0 + row) * kE + kt + 8 * sc),
          (lvoid_t*)(As + slot * 512), 16, 0, 0);
      __builtin_amdgcn_global_load_lds(
          (gvoid_t*)(BT + (size_t)(n0 + row) * kE + kt + 8 * sc),
          (lvoid_t*)(Bs + slot * 512), 16, 0, 0);
    }
    __syncthreads();
    #pragma unroll
    for (int kk = 0; kk < 2; ++kk) {
      bf16x8 af[4], bfr[4];
      #pragma unroll
      for (int m = 0; m < 4; ++m)
        af[m] = *(const bf16x8*)(As + (wr * 64 + m * 16 + lr) * 64 + (((4 * kk + g) ^ swz) << 3));
      #pragma unroll
      for (int n = 0; n < 4; ++n)
        bfr[n] = *(const bf16x8*)(Bs + (wc * 64 + n * 16 + lr) * 64 + (((4 * kk + g) ^ swz) << 3));
      __builtin_amdgcn_s_setprio(1);
      #pragma unroll
      for (int m = 0; m < 4; ++m)
        #pragma unroll
        for (int n = 0; n < 4; ++n)
          acc[m][n] = __builtin_amdgcn_mfma_f32_16x16x32_bf16(af[m], bfr[n], acc[m][n], 0, 0, 0);
      __builtin_amdgcn_s_setprio(0);
    }
    __syncthreads();
  }

  // ---- normal (row-major) C write: K blocks -> Kb, Q blocks -> Qb ----
  short* C = (n0 < 1024) ? Kb : Qb;
  const float scale = (n0 < 1024) ? 1.0f : qs;
  const int crow = m0 + wr * 64, ccol = (n0 & 1023) + wc * 64;
  #pragma unroll
  for (int m = 0; m < 4; ++m)
    #pragma unroll
    for (int n = 0; n < 4; ++n)
      #pragma unroll
      for (int r = 0; r < 4; ++r)
        C[(size_t)(crow + m * 16 + 4 * g + r) * kE + ccol + n * 16 + lr] =
            bfc(acc[m][n][r] * scale);

  // ---- K blocks additionally emit the transposed copy KT[(b*16+h)*64+s][t] ----
  // via LDS (reuse SMp; last loop barrier guarantees As/Bs reads are done).
  if (n0 < 1024) {
    const int b = m0 >> 11;          // batch (m-panel is within one batch)
    const int tloc = m0 & 2047;      // t offset within batch
    short* Lt = SMp;                 // [64 cols][136 t-stride] = 17.4 KB
    #pragma unroll
    for (int half = 0; half < 2; ++half) {
      __syncthreads();               // previous-phase LDS reads done
      if (wc == half) {
        #pragma unroll
        for (int m = 0; m < 4; ++m)
          #pragma unroll
          for (int n = 0; n < 4; ++n) {
            u32x2 e;
            e[0] = cvt_pk(acc[m][n][0], acc[m][n][1]);
            e[1] = cvt_pk(acc[m][n][2], acc[m][n][3]);
            *(u32x2*)(Lt + (n * 16 + lr) * 136 + wr * 64 + m * 16 + 4 * g) = e;
          }
      }
      __syncthreads();
      const int sc = tid >> 2;                    // s 0..63
      const int h = (n0 >> 6) + half;             // head
      short* ktrow = KT + ((size_t)(b * 16 + h) * 64 + sc) * kT + tloc;
      #pragma unroll
      for (int i = 0; i < 4; ++i) {
        const int t4 = (tid & 3) * 32 + i * 8;    // 8 shorts per read
        u32x4 v = *(const u32x4*)(Lt + sc * 136 + t4);
        *(u32x4*)(ktrow + t4) = v;
      }
    }
  }
}

// ---------------- bf16 GEMM (m97 recipe): C = A @ BT^T + bias (f32 out) ----------------
__global__ __launch_bounds__(256)
void gemm_bt(const short* __restrict__ A, const short* __restrict__ BT,
             float* __restrict__ C, const float* __restrict__ bias,
             int M, int N, int K) {
  __shared__ short As[128 * 64];
  __shared__ short Bs[128 * 64];
  const int tid = threadIdx.x;
  const int w = tid >> 6, lane = tid & 63;
  const int g = lane >> 4, lr = lane & 15;
  const int bid = blockIdx.x;
  const int id = (bid & 7) * 64 + (bid >> 3);   // 512 % 8 == 0
  const int n0 = (id & 7) * 128, m0 = (id >> 3) * 128;
  const int wr = w >> 1, wc = w & 1;
  const int srow = lane >> 3, sch = lane & 7;
  const int swz = lr & 7;

  f32x4 acc[4][4];
  #pragma unroll
  for (int m = 0; m < 4; ++m)
    #pragma unroll
    for (int n = 0; n < 4; ++n)
      #pragma unroll
      for (int r = 0; r < 4; ++r) acc[m][n][r] = 0.f;

  for (int kt = 0; kt < K; kt += 64) {
    #pragma unroll
    for (int i = 0; i < 4; ++i) {
      const int slot = w * 4 + i;
      const int row = slot * 8 + srow;
      const int sc = sch ^ srow;
      __builtin_amdgcn_global_load_lds(
          (gvoid_t*)(A + (size_t)(m0 + row) * K + kt + 8 * sc),
          (lvoid_t*)(As + slot * 512), 16, 0, 0);
      __builtin_amdgcn_global_load_lds(
          (gvoid_t*)(BT + (size_t)(n0 + row) * K + kt + 8 * sc),
          (lvoid_t*)(Bs + slot * 512), 16, 0, 0);
    }
    __syncthreads();
    #pragma unroll
    for (int kk = 0; kk < 2; ++kk) {
      bf16x8 af[4], bfr[4];
      #pragma unroll
      for (int m = 0; m < 4; ++m)
        af[m] = *(const bf16x8*)(As + (wr * 64 + m * 16 + lr) * 64 + (((4 * kk + g) ^ swz) << 3));
      #pragma unroll
      for (int n = 0; n < 4; ++n)
        bfr[n] = *(const bf16x8*)(Bs + (wc * 64 + n * 16 + lr) * 64 + (((4 * kk + g) ^ swz) << 3));
      __builtin_amdgcn_s_setprio(1);
      #pragma unroll
      for (int m = 0; m < 4; ++m)
        #pragma unroll
        for (int n = 0; n < 4; ++n)
          acc[m][n] = __builtin_amdgcn_mfma_f32_16x16x32_bf16(af[m], bfr[n], acc[m][n], 0, 0, 0);
      __builtin_amdgcn_s_setprio(0);
    }
    __syncthreads();
  }

  const int crow = m0 + wr * 64, ccol = n0 + wc * 64;
  float bv[4];
  #pragma unroll
  for (int n = 0; n < 4; ++n) bv[n] = bias[ccol + n * 16 + lr];
  #pragma unroll
  for (int m = 0; m < 4; ++m)
    #pragma unroll
    for (int n = 0; n < 4; ++n)
      #pragma unroll
      for (int r = 0; r < 4; ++r)
        C[(size_t)(crow + m * 16 + 4 * g + r) * N + ccol + n * 16 + lr] =
            acc[m][n][r] + bv[n];
}

// ---------------- flash attention; V == K (faithful to reference bug) ----------------
// 32x32 swapped structure. STATIC softmax m=0 (shift-invariant; |s| < ~2 here).
// Q pre-scaled by E^-0.5 * log2(e) so P = exp2(s').
// l MUST be the f32 lsum + shfl_xor(32) path (ones-MFMA l failed on HW twice:
// R6/R8 at 1.9e-2 - do not reintroduce).
// P -> PV B-frags in-register via cvt_pk + permlane32_swap (T12).
// Staging: Kt [kv][s] / Vt [s][kv] via coalesced global_load_lds,
// double-buffered, XOR-chunk-swizzled source, one barrier per tile.
// Epilogue reuses staging pool (4 waves x 32 x 68 = 8704 <= 16384 shorts).
__global__ __launch_bounds__(256, 4)
void attn_kernel(const short* Qb, const short* __restrict__ Kb,
                 const short* __restrict__ KT, short* AO) {
  __shared__ short SM[16384];   // 32 KB: Kt[2] @ 0/4096, Vt[2] @ 8192/12288

  const int tid = threadIdx.x;
  const int w = tid >> 6, lane = tid & 63;
  const int l31 = lane & 31, hi = lane >> 5;
  const int swz = l31 & 7;
  const int bid = blockIdx.x;
  const int id = (bid & 7) * 128 + (bid >> 3);  // XCD swizzle (1024 % 8 == 0)
  const int q0 = (id & 15) * 128;
  const int bh = id >> 4;                       // b*16 + h
  const size_t base = (size_t)(bh >> 4) * kT * kE + (size_t)(bh & 15) * kS;
  const short* Kbh = Kb + base;
  const short* KTbh = KT + (size_t)bh * 64 * kT;

  const int srow_lo = lane >> 3, sch = lane & 7;

  // ---- prologue: issue tile-0 staging ----
  #pragma unroll
  for (int i = 0; i < 2; ++i) {
    const int slot = w * 2 + i, row = slot * 8 + srow_lo;
    const int sc = sch ^ (row & 7);
    __builtin_amdgcn_global_load_lds(
        (gvoid_t*)(Kbh + (size_t)row * kE + 8 * sc),
        (lvoid_t*)(SM + slot * 512), 16, 0, 0);
    __builtin_amdgcn_global_load_lds(
        (gvoid_t*)(KTbh + (size_t)row * kT + 8 * sc),
        (lvoid_t*)(SM + 8192 + slot * 512), 16, 0, 0);
  }

  bf16x8 qB[4];
  #pragma unroll
  for (int ks = 0; ks < 4; ++ks)
    qB[ks] = *(const bf16x8*)(Qb + base +
        (size_t)(q0 + w * 32 + l31) * kE + ks * 16 + hi * 8);

  f32x16 oacc[2];
  #pragma unroll
  for (int r = 0; r < 16; ++r) { oacc[0][r] = 0.f; oacc[1][r] = 0.f; }
  float lsum = 0.f;

  for (int t = 0; t < 32; ++t) {
    __syncthreads();   // tile-t staging drained; prev-tile reads complete

    // ---- issue tile t+1 staging (hidden under this tile's compute) ----
    if (t < 31) {
      const short* kbt = Kbh + (size_t)(t + 1) * 64 * kE;
      const short* vtt = KTbh + (size_t)(t + 1) * 64;
      short* KtN = SM + ((t + 1) & 1) * 4096;
      short* VtN = SM + 8192 + ((t + 1) & 1) * 4096;
      #pragma unroll
      for (int i = 0; i < 2; ++i) {
        const int slot = w * 2 + i, row = slot * 8 + srow_lo;
        const int sc = sch ^ (row & 7);
        __builtin_amdgcn_global_load_lds(
            (gvoid_t*)(kbt + (size_t)row * kE + 8 * sc),
            (lvoid_t*)(KtN + slot * 512), 16, 0, 0);
        __builtin_amdgcn_global_load_lds(
            (gvoid_t*)(vtt + (size_t)row * kT + 8 * sc),
            (lvoid_t*)(VtN + slot * 512), 16, 0, 0);
      }
    }

    const short* KtC = SM + (t & 1) * 4096;
    const short* VtC = SM + 8192 + (t & 1) * 4096;

    // ---- S^T = K Q^T (32x32x16) ----
    f32x16 sacc[2];
    #pragma unroll
    for (int r = 0; r < 16; ++r) { sacc[0][r] = 0.f; sacc[1][r] = 0.f; }
    #pragma unroll
    for (int ks = 0; ks < 4; ++ks) {
      const int pc = ((2 * ks + hi) ^ swz) << 3;
      bf16x8 kf0 = *(const bf16x8*)(KtC + (l31)      * 64 + pc);
      bf16x8 kf1 = *(const bf16x8*)(KtC + (32 + l31) * 64 + pc);
      __builtin_amdgcn_s_setprio(1);
      sacc[0] = __builtin_amdgcn_mfma_f32_32x32x16_bf16(kf0, qB[ks], sacc[0], 0, 0, 0);
      sacc[1] = __builtin_amdgcn_mfma_f32_32x32x16_bf16(kf1, qB[ks], sacc[1], 0, 0, 0);
      __builtin_amdgcn_s_setprio(0);
    }

    // ---- P = exp2(S^T); f32 lsum; build PV B-frags in-register (T12) ----
    union { unsigned u[4]; bf16x8 v; } pf[4];
    #pragma unroll
    for (int kvf = 0; kvf < 2; ++kvf) {
      float pe[16];
      #pragma unroll
      for (int r = 0; r < 16; ++r) {
        pe[r] = fexp2(sacc[kvf][r]);
        lsum += pe[r];
      }
      #pragma unroll
      for (int sub = 0; sub < 2; ++sub) {
        unsigned a0 = cvt_pk(pe[8 * sub + 0], pe[8 * sub + 1]);
        unsigned b0 = cvt_pk(pe[8 * sub + 4], pe[8 * sub + 5]);
        plane_swap(a0, b0);
        unsigned a1 = cvt_pk(pe[8 * sub + 2], pe[8 * sub + 3]);
        unsigned b1 = cvt_pk(pe[8 * sub + 6], pe[8 * sub + 7]);
        plane_swap(a1, b1);
        pf[2 * kvf + sub].u[0] = a0;
        pf[2 * kvf + sub].u[1] = a1;
        pf[2 * kvf + sub].u[2] = b0;
        pf[2 * kvf + sub].u[3] = b1;
      }
    }

    // ---- O^T += V^T P^T ----
    #pragma unroll
    for (int ks = 0; ks < 4; ++ks) {
      const int pc = ((2 * ks + hi) ^ swz) << 3;
      bf16x8 vf0 = *(const bf16x8*)(VtC + (l31)      * 64 + pc);
      bf16x8 vf1 = *(const bf16x8*)(VtC + (32 + l31) * 64 + pc);
      __builtin_amdgcn_s_setprio(1);
      oacc[0] = __builtin_amdgcn_mfma_f32_32x32x16_bf16(vf0, pf[ks].v, oacc[0], 0, 0, 0);
      oacc[1] = __builtin_amdgcn_mfma_f32_32x32x16_bf16(vf1, pf[ks].v, oacc[1], 0, 0, 0);
      __builtin_amdgcn_s_setprio(0);
    }
  }

  __syncthreads();   // all PV reads done before reusing the pool for O transpose

  // ---- epilogue: O = O^T / l via pool-reuse Ot (stride 68), coalesced stores ----
  const float ltot = lsum + __shfl_xor(lsum, 32);  // lane pair (q=l31) holds halves
  const float inv = 1.f / ltot;
  short* OtW = SM + w * 2176;        // 32 q x 68 per wave; 4*2176=8704 <= 16384
  #pragma unroll
  for (int sf = 0; sf < 2; ++sf)
    #pragma unroll
    for (int c = 0; c < 4; ++c) {
      u32x2 e;
      e[0] = cvt_pk(oacc[sf][4 * c + 0] * inv, oacc[sf][4 * c + 1] * inv);
      e[1] = cvt_pk(oacc[sf][4 * c + 2] * inv, oacc[sf][4 * c + 3] * inv);
      *(u32x2*)(OtW + l31 * 68 + sf * 32 + 8 * c + 4 * hi) = e;
    }
  __builtin_amdgcn_s_barrier();
  #pragma unroll
  for (int i = 0; i < 8; ++i) {
    const int row = i * 4 + (lane >> 4);
    u32x2 v = *(const u32x2*)(OtW + row * 68 + (lane & 15) * 4);
    *(u32x2*)(AO + base + (size_t)(q0 + w * 32 + row) * kE + (lane & 15) * 4) = v;
  }
}

// ---------------- launch ----------------
extern "C" void kernel_launch(void* const* d_in, const int* in_sizes, int n_in,
                              void* d_out, int out_size, void* d_ws, size_t ws_size,
                              hipStream_t stream) {
  const float* x  = (const float*)d_in[0];
  const float* Wk = (const float*)d_in[1];
  const float* Wq = (const float*)d_in[2];
  const float* Wo = (const float*)d_in[3];
  const float* bo = (const float*)d_in[4];
  float* out = (float*)d_out;

  const size_t nXE = (size_t)kRows * kE;  // 8388608
  const size_t nW  = (size_t)kE * kE;     // 1048576

  short* Xb   = (short*)d_ws;
  short* Kb   = Xb   + nXE;
  short* Qb   = Kb   + nXE;
  short* WkqT = Qb   + nXE;          // [2048][1024]
  short* WoT  = WkqT + 2 * nW;
  short* KTb  = (short*)d_out;  // scratch in out: 16.8 MB bf16 <= 33.5 MB; gemm_bt
                                // fully overwrites out afterwards (stream-ordered)
  short* AO   = Qb;   // reuse: each block reads its own Qb rows into regs first

  // fused x->bf16 + W transposes (1 launch instead of 4)
  prep<<<dim3(8192 + 3 * 1024), 256, 0, stream>>>(
      x, Wk, Wq, Wo, Xb, WkqT, WoT);

  // Fused K(=V) and Q projections; Q scaled by E^-0.5 * log2(e);
  // K blocks also emit the transposed KT (replaces the transv kernel).
  gemm_kq<<<dim3(1024), 256, 0, stream>>>(
      Xb, WkqT, Kb, Qb, KTb, 0.03125f * 1.44269504f);

  attn_kernel<<<dim3(1024), 256, 0, stream>>>(Qb, Kb, KTb, AO);

  gemm_bt<<<dim3(512), 256, 0, stream>>>(
      AO, WoT, out, bo, kRows, kE, kE);
}

// Round 11
// 161.975 us; speedup vs baseline: 1.5063x; 1.0650x over previous
//
#include <hip/hip_runtime.h>
#include <hip/hip_bf16.h>
#include <stdint.h>

// Problem constants
static constexpr int kB = 4;
static constexpr int kT = 2048;
static constexpr int kE = 1024;
static constexpr int kH = 16;
static constexpr int kS = 64;          // head dim
static constexpr int kRows = kB * kT;  // 8192

typedef __attribute__((ext_vector_type(4)))  float    f32x4;
typedef __attribute__((ext_vector_type(16))) float    f32x16;
typedef __attribute__((ext_vector_type(4)))  float    float4v;
typedef __attribute__((ext_vector_type(8)))  __bf16   bf16x8;
typedef __attribute__((ext_vector_type(8)))  short    short8v;
typedef __attribute__((ext_vector_type(4)))  short    short4v;
typedef __attribute__((ext_vector_type(2)))  unsigned u32x2;
typedef __attribute__((ext_vector_type(4)))  unsigned u32x4;

typedef const __attribute__((address_space(1))) void gvoid_t;
typedef __attribute__((address_space(3))) void lvoid_t;

__device__ __forceinline__ short f2bf(float f) {
  union { float f; unsigned u; } c; c.f = f;
  unsigned r = (c.u + 0x7FFFu + ((c.u >> 16) & 1u)) >> 16;
  return (short)(r & 0xFFFFu);
}

__device__ __forceinline__ short bfc(float f) {
  union { __bf16 b; short s; } u; u.b = (__bf16)f; return u.s;
}

// v_cvt_pk_bf16_f32: D[15:0]=bf16(lo), D[31:16]=bf16(hi).
__device__ __forceinline__ unsigned cvt_pk(float lo, float hi) {
  unsigned r;
  asm("v_cvt_pk_bf16_f32 %0, %1, %2" : "=v"(r) : "v"(lo), "v"(hi));
  return r;
}

// v_permlane32_swap_b32: a' = [a.lo, b.lo], b' = [a.hi, b.hi]
__device__ __forceinline__ void plane_swap(unsigned& a, unsigned& b) {
  asm("v_permlane32_swap_b32 %0, %1" : "+v"(a), "+v"(b));
}

#if __has_builtin(__builtin_amdgcn_exp2f)
__device__ __forceinline__ float fexp2(float x) { return __builtin_amdgcn_exp2f(x); }
#else
__device__ __forceinline__ float fexp2(float x) { return exp2f(x); }
#endif

// ---------------- fused prologue: x->bf16 + three W transposes ----------------
__global__ __launch_bounds__(256)
void prep(const float* __restrict__ x, const float* __restrict__ Wk,
          const float* __restrict__ Wq, const float* __restrict__ Wo,
          short* __restrict__ Xb, short* __restrict__ WkqT,
          short* __restrict__ WoT) {
  const int bid = blockIdx.x;
  if (bid < 8192) {
    size_t i = ((size_t)bid * 256 + threadIdx.x) * 4;
    float4v v = *(const float4v*)(x + i);
    short4v o;
    o[0] = f2bf(v[0]); o[1] = f2bf(v[1]); o[2] = f2bf(v[2]); o[3] = f2bf(v[3]);
    *(short4v*)(Xb + i) = o;
    return;
  }
  __shared__ float tile[32][33];
  const int tb = bid - 8192;
  const int which = tb >> 10, t = tb & 1023;
  const float* W = (which == 0) ? Wk : ((which == 1) ? Wq : Wo);
  short* WT = (which == 0) ? WkqT : ((which == 1) ? (WkqT + kE * kE) : WoT);
  const int tx = threadIdx.x & 31, ty = threadIdx.x >> 5;  // 32 x 8
  const int c = (t & 31) * 32, r = (t >> 5) * 32;
  #pragma unroll
  for (int i = ty; i < 32; i += 8)
    tile[i][tx] = W[(size_t)(r + i) * kE + c + tx];
  __syncthreads();
  #pragma unroll
  for (int i = ty; i < 32; i += 8)
    WT[(size_t)(c + i) * kE + r + tx] = f2bf(tile[tx][i]);
}

// ---------------- 256^2 8-wave phase-split K+Q projection GEMM ----------------
// BM=BN=256, BK=64, 512 threads (2M x 4N waves), LDS 128 KB (A+B double buf).
// Per K-tile: 4 phases {ds_read quadrant frags; stage next tile (A@p1, B@p2);
// barrier; lgkmcnt(0); setprio(1); 16 MFMA; setprio(0); barrier}; vmcnt(0)
// once per K-tile at phase 4 (stages are 2-3 phases old by then).
// n-tile < 4 -> Kb (scale 1) + transposed KT[(b*16+h)*64+s][t]; else Qb (qs).

__device__ __forceinline__ void kq_stageA(
    const short* __restrict__ gA, short* nA, int wid, int sl, int sc7) {
  #pragma unroll
  for (int h = 0; h < 2; ++h)
    #pragma unroll
    for (int i = 0; i < 2; ++i) {
      const int slot = wid * 2 + i;
      const int row = slot * 8 + sl;           // row within 128-row half
      const int sc = sc7 ^ (row & 7);
      __builtin_amdgcn_global_load_lds(
          (gvoid_t*)(gA + (size_t)(h * 128 + row) * kE + 8 * sc),
          (lvoid_t*)(nA + h * 8192 + slot * 512), 16, 0, 0);
    }
}

__device__ __forceinline__ void kq_tile(
    const short* __restrict__ gA, const short* __restrict__ gB,  // next k-tile
    const short* cA, const short* cB, short* nA, short* nB,
    bool stage, f32x4 (&acc)[8][4],
    int wid, int wm, int wn, int g, int lr, int sl, int sc7) {
  const int swz = lr & 7;
  const short* cAw = cA + wm * 8192;                  // wave's A half-tile
  const short* cBw = cB + (wn >> 1) * 8192;           // wave's B half-tile
  const int brow0 = (wn & 1) * 64;                    // wave's B row base in half
  bf16x8 af[4][2], b0[2][2], b1[2][2];

  // ================= phase 1: quadrant (Mh0, Nh0) =================
  #pragma unroll
  for (int mf = 0; mf < 4; ++mf)
    #pragma unroll
    for (int kk = 0; kk < 2; ++kk)
      af[mf][kk] = *(const bf16x8*)(cAw + (mf * 16 + lr) * 64 + (((4 * kk + g) ^ swz) << 3));
  #pragma unroll
  for (int nf = 0; nf < 2; ++nf)
    #pragma unroll
    for (int kk = 0; kk < 2; ++kk)
      b0[nf][kk] = *(const bf16x8*)(cBw + (brow0 + nf * 16 + lr) * 64 + (((4 * kk + g) ^ swz) << 3));
  if (stage) kq_stageA(gA, nA, wid, sl, sc7);
  asm volatile("" ::: "memory");
  __builtin_amdgcn_s_barrier();
  asm volatile("s_waitcnt lgkmcnt(0)" ::: "memory");
  __builtin_amdgcn_sched_barrier(0);
  __builtin_amdgcn_s_setprio(1);
  #pragma unroll
  for (int mf = 0; mf < 4; ++mf)
    #pragma unroll
    for (int nf = 0; nf < 2; ++nf)
      #pragma unroll
      for (int kk = 0; kk < 2; ++kk)
        acc[mf][nf] = __builtin_amdgcn_mfma_f32_16x16x32_bf16(af[mf][kk], b0[nf][kk], acc[mf][nf], 0, 0, 0);
  __builtin_amdgcn_s_setprio(0);
  asm volatile("" ::: "memory");
  __builtin_amdgcn_s_barrier();

  // ================= phase 2: quadrant (Mh0, Nh1) =================
  #pragma unroll
  for (int nf = 0; nf < 2; ++nf)
    #pragma unroll
    for (int kk = 0; kk < 2; ++kk)
      b1[nf][kk] = *(const bf16x8*)(cBw + (brow0 + 32 + nf * 16 + lr) * 64 + (((4 * kk + g) ^ swz) << 3));
  if (stage) kq_stageA(gB, nB, wid, sl, sc7);
  asm volatile("" ::: "memory");
  __builtin_amdgcn_s_barrier();
  asm volatile("s_waitcnt lgkmcnt(0)" ::: "memory");
  __builtin_amdgcn_sched_barrier(0);
  __builtin_amdgcn_s_setprio(1);
  #pragma unroll
  for (int mf = 0; mf < 4; ++mf)
    #pragma unroll
    for (int nf = 0; nf < 2; ++nf)
      #pragma unroll
      for (int kk = 0; kk < 2; ++kk)
        acc[mf][2 + nf] = __builtin_amdgcn_mfma_f32_16x16x32_bf16(af[mf][kk], b1[nf][kk], acc[mf][2 + nf], 0, 0, 0);
  __builtin_amdgcn_s_setprio(0);
  asm volatile("" ::: "memory");
  __builtin_amdgcn_s_barrier();

  // ================= phase 3: quadrant (Mh1, Nh1) =================
  #pragma unroll
  for (int mf = 0; mf < 4; ++mf)
    #pragma unroll
    for (int kk = 0; kk < 2; ++kk)
      af[mf][kk] = *(const bf16x8*)(cAw + (64 + mf * 16 + lr) * 64 + (((4 * kk + g) ^ swz) << 3));
  asm volatile("" ::: "memory");
  __builtin_amdgcn_s_barrier();
  asm volatile("s_waitcnt lgkmcnt(0)" ::: "memory");
  __builtin_amdgcn_sched_barrier(0);
  __builtin_amdgcn_s_setprio(1);
  #pragma unroll
  for (int mf = 0; mf < 4; ++mf)
    #pragma unroll
    for (int nf = 0; nf < 2; ++nf)
      #pragma unroll
      for (int kk = 0; kk < 2; ++kk)
        acc[4 + mf][2 + nf] = __builtin_amdgcn_mfma_f32_16x16x32_bf16(af[mf][kk], b1[nf][kk], acc[4 + mf][2 + nf], 0, 0, 0);
  __builtin_amdgcn_s_setprio(0);
  asm volatile("" ::: "memory");
  __builtin_amdgcn_s_barrier();

  // ================= phase 4: quadrant (Mh1, Nh0) =================
  #pragma unroll
  for (int nf = 0; nf < 2; ++nf)
    #pragma unroll
    for (int kk = 0; kk < 2; ++kk)
      b0[nf][kk] = *(const bf16x8*)(cBw + (brow0 + nf * 16 + lr) * 64 + (((4 * kk + g) ^ swz) << 3));
  asm volatile("s_waitcnt vmcnt(0)" ::: "memory");   // next tile's stages landed
  asm volatile("" ::: "memory");
  __builtin_amdgcn_s_barrier();
  asm volatile("s_waitcnt lgkmcnt(0)" ::: "memory");
  __builtin_amdgcn_sched_barrier(0);
  __builtin_amdgcn_s_setprio(1);
  #pragma unroll
  for (int mf = 0; mf < 4; ++mf)
    #pragma unroll
    for (int nf = 0; nf < 2; ++nf)
      #pragma unroll
      for (int kk = 0; kk < 2; ++kk)
        acc[4 + mf][nf] = __builtin_amdgcn_mfma_f32_16x16x32_bf16(af[mf][kk], b0[nf][kk], acc[4 + mf][nf], 0, 0, 0);
  __builtin_amdgcn_s_setprio(0);
  asm volatile("" ::: "memory");
  __builtin_amdgcn_s_barrier();
}

__global__ __launch_bounds__(512)
void gemm_kq8(const short* __restrict__ A, const short* __restrict__ BT,
              short* __restrict__ Kb, short* __restrict__ Qb,
              short* __restrict__ KT, float qs) {
  __shared__ short LA[2][16384];   // 64 KB: A tiles (256x64 per buf)
  __shared__ short LB[2][16384];   // 64 KB: B tiles

  const int tid = threadIdx.x;
  const int wid = tid >> 6, lane = tid & 63;
  const int g = lane >> 4, lr = lane & 15;
  const int wm = wid >> 2, wn = wid & 3;    // 2M x 4N waves
  const int sl = lane >> 3, sc7 = lane & 7;
  const int bid = blockIdx.x;
  const int id = (bid & 7) * 32 + (bid >> 3);   // XCD swizzle (256 % 8 == 0)
  const int n0 = (id & 7) * 256, m0 = (id >> 3) * 256;

  const short* Abase = A + (size_t)m0 * kE;
  const short* Bbase = BT + (size_t)n0 * kE;

  f32x4 acc[8][4];
  #pragma unroll
  for (int mf = 0; mf < 8; ++mf)
    #pragma unroll
    for (int nf = 0; nf < 4; ++nf)
      #pragma unroll
      for (int r = 0; r < 4; ++r) acc[mf][nf][r] = 0.f;

  // ---- prologue: stage K-tile 0 into buf 0, full drain (one-time) ----
  kq_stageA(Abase, &LA[0][0], wid, sl, sc7);
  kq_stageA(Bbase, &LB[0][0], wid, sl, sc7);
  asm volatile("s_waitcnt vmcnt(0)" ::: "memory");
  __syncthreads();

  // ---- main loop: 16 K-tiles, 2 per iteration (static dbuf indices) ----
  for (int ktp = 0; ktp < 8; ++ktp) {
    kq_tile(Abase + (2 * ktp + 1) * 64, Bbase + (2 * ktp + 1) * 64,
            &LA[0][0], &LB[0][0], &LA[1][0], &LB[1][0],
            true, acc, wid, wm, wn, g, lr, sl, sc7);
    kq_tile(Abase + (2 * ktp + 2) * 64, Bbase + (2 * ktp + 2) * 64,
            &LA[1][0], &LB[1][0], &LA[0][0], &LB[0][0],
            (2 * ktp + 1) < 15, acc, wid, wm, wn, g, lr, sl, sc7);
  }

  // ---- epilogue ----
  const int isq = (n0 >= 1024);
  short* Crm = isq ? Qb : Kb;
  const float scale = isq ? qs : 1.0f;
  const int crow = m0 + wm * 128, ccol = (n0 & 1023) + wn * 64;
  #pragma unroll
  for (int mf = 0; mf < 8; ++mf)
    #pragma unroll
    for (int nf = 0; nf < 4; ++nf)
      #pragma unroll
      for (int r = 0; r < 4; ++r)
        Crm[(size_t)(crow + mf * 16 + 4 * g + r) * kE + ccol + nf * 16 + lr] =
            bfc(acc[mf][nf][r] * scale);
  if (!isq) {
    // transposed copy KT[(b*16+h)*64 + s][t]  (r-packed 8B stores)
    const int b = m0 >> 11, tloc = (m0 & 2047) + wm * 128;
    const int h = (n0 + wn * 64) >> 6;
    #pragma unroll
    for (int mf = 0; mf < 8; ++mf)
      #pragma unroll
      for (int nf = 0; nf < 4; ++nf) {
        u32x2 e;
        e[0] = cvt_pk(acc[mf][nf][0], acc[mf][nf][1]);
        e[1] = cvt_pk(acc[mf][nf][2], acc[mf][nf][3]);
        *(u32x2*)(KT + (size_t)((b * 16 + h) * 64 + nf * 16 + lr) * kT +
                  tloc + mf * 16 + 4 * g) = e;
      }
  }
}

// ---------------- bf16 GEMM (m97 recipe): C = A @ BT^T + bias (f32 out) ----------------
__global__ __launch_bounds__(256)
void gemm_bt(const short* __restrict__ A, const short* __restrict__ BT,
             float* __restrict__ C, const float* __restrict__ bias,
             int M, int N, int K) {
  __shared__ short As[128 * 64];
  __shared__ short Bs[128 * 64];
  const int tid = threadIdx.x;
  const int w = tid >> 6, lane = tid & 63;
  const int g = lane >> 4, lr = lane & 15;
  const int bid = blockIdx.x;
  const int id = (bid & 7) * 64 + (bid >> 3);   // 512 % 8 == 0
  const int n0 = (id & 7) * 128, m0 = (id >> 3) * 128;
  const int wr = w >> 1, wc = w & 1;
  const int srow = lane >> 3, sch = lane & 7;
  const int swz = lr & 7;

  f32x4 acc[4][4];
  #pragma unroll
  for (int m = 0; m < 4; ++m)
    #pragma unroll
    for (int n = 0; n < 4; ++n)
      #pragma unroll
      for (int r = 0; r < 4; ++r) acc[m][n][r] = 0.f;

  for (int kt = 0; kt < K; kt += 64) {
    #pragma unroll
    for (int i = 0; i < 4; ++i) {
      const int slot = w * 4 + i;
      const int row = slot * 8 + srow;
      const int sc = sch ^ srow;
      __builtin_amdgcn_global_load_lds(
          (gvoid_t*)(A + (size_t)(m0 + row) * K + kt + 8 * sc),
          (lvoid_t*)(As + slot * 512), 16, 0, 0);
      __builtin_amdgcn_global_load_lds(
          (gvoid_t*)(BT + (size_t)(n0 + row) * K + kt + 8 * sc),
          (lvoid_t*)(Bs + slot * 512), 16, 0, 0);
    }
    __syncthreads();
    #pragma unroll
    for (int kk = 0; kk < 2; ++kk) {
      bf16x8 af[4], bfr[4];
      #pragma unroll
      for (int m = 0; m < 4; ++m)
        af[m] = *(const bf16x8*)(As + (wr * 64 + m * 16 + lr) * 64 + (((4 * kk + g) ^ swz) << 3));
      #pragma unroll
      for (int n = 0; n < 4; ++n)
        bfr[n] = *(const bf16x8*)(Bs + (wc * 64 + n * 16 + lr) * 64 + (((4 * kk + g) ^ swz) << 3));
      __builtin_amdgcn_s_setprio(1);
      #pragma unroll
      for (int m = 0; m < 4; ++m)
        #pragma unroll
        for (int n = 0; n < 4; ++n)
          acc[m][n] = __builtin_amdgcn_mfma_f32_16x16x32_bf16(af[m], bfr[n], acc[m][n], 0, 0, 0);
      __builtin_amdgcn_s_setprio(0);
    }
    __syncthreads();
  }

  const int crow = m0 + wr * 64, ccol = n0 + wc * 64;
  float bv[4];
  #pragma unroll
  for (int n = 0; n < 4; ++n) bv[n] = bias[ccol + n * 16 + lr];
  #pragma unroll
  for (int m = 0; m < 4; ++m)
    #pragma unroll
    for (int n = 0; n < 4; ++n)
      #pragma unroll
      for (int r = 0; r < 4; ++r)
        C[(size_t)(crow + m * 16 + 4 * g + r) * N + ccol + n * 16 + lr] =
            acc[m][n][r] + bv[n];
}

// ---------------- flash attention; V == K (faithful to reference bug) ----------------
// 32x32 swapped structure. STATIC softmax m=0 (shift-invariant; |s| < ~2 here).
// Q pre-scaled by E^-0.5 * log2(e) so P = exp2(s').
// l MUST be the f32 lsum + shfl_xor(32) path (ones-MFMA l failed on HW twice:
// R6/R8 at 1.9e-2 - do not reintroduce).
__global__ __launch_bounds__(256, 4)
void attn_kernel(const short* Qb, const short* __restrict__ Kb,
                 const short* __restrict__ KT, short* AO) {
  __shared__ short SM[16384];   // 32 KB: Kt[2] @ 0/4096, Vt[2] @ 8192/12288

  const int tid = threadIdx.x;
  const int w = tid >> 6, lane = tid & 63;
  const int l31 = lane & 31, hi = lane >> 5;
  const int swz = l31 & 7;
  const int bid = blockIdx.x;
  const int id = (bid & 7) * 128 + (bid >> 3);  // XCD swizzle (1024 % 8 == 0)
  const int q0 = (id & 15) * 128;
  const int bh = id >> 4;                       // b*16 + h
  const size_t base = (size_t)(bh >> 4) * kT * kE + (size_t)(bh & 15) * kS;
  const short* Kbh = Kb + base;
  const short* KTbh = KT + (size_t)bh * 64 * kT;

  const int srow_lo = lane >> 3, sch = lane & 7;

  #pragma unroll
  for (int i = 0; i < 2; ++i) {
    const int slot = w * 2 + i, row = slot * 8 + srow_lo;
    const int sc = sch ^ (row & 7);
    __builtin_amdgcn_global_load_lds(
        (gvoid_t*)(Kbh + (size_t)row * kE + 8 * sc),
        (lvoid_t*)(SM + slot * 512), 16, 0, 0);
    __builtin_amdgcn_global_load_lds(
        (gvoid_t*)(KTbh + (size_t)row * kT + 8 * sc),
        (lvoid_t*)(SM + 8192 + slot * 512), 16, 0, 0);
  }

  bf16x8 qB[4];
  #pragma unroll
  for (int ks = 0; ks < 4; ++ks)
    qB[ks] = *(const bf16x8*)(Qb + base +
        (size_t)(q0 + w * 32 + l31) * kE + ks * 16 + hi * 8);

  f32x16 oacc[2];
  #pragma unroll
  for (int r = 0; r < 16; ++r) { oacc[0][r] = 0.f; oacc[1][r] = 0.f; }
  float lsum = 0.f;

  for (int t = 0; t < 32; ++t) {
    __syncthreads();

    if (t < 31) {
      const short* kbt = Kbh + (size_t)(t + 1) * 64 * kE;
      const short* vtt = KTbh + (size_t)(t + 1) * 64;
      short* KtN = SM + ((t + 1) & 1) * 4096;
      short* VtN = SM + 8192 + ((t + 1) & 1) * 4096;
      #pragma unroll
      for (int i = 0; i < 2; ++i) {
        const int slot = w * 2 + i, row = slot * 8 + srow_lo;
        const int sc = sch ^ (row & 7);
        __builtin_amdgcn_global_load_lds(
            (gvoid_t*)(kbt + (size_t)row * kE + 8 * sc),
            (lvoid_t*)(KtN + slot * 512), 16, 0, 0);
        __builtin_amdgcn_global_load_lds(
            (gvoid_t*)(vtt + (size_t)row * kT + 8 * sc),
            (lvoid_t*)(VtN + slot * 512), 16, 0, 0);
      }
    }

    const short* KtC = SM + (t & 1) * 4096;
    const short* VtC = SM + 8192 + (t & 1) * 4096;

    f32x16 sacc[2];
    #pragma unroll
    for (int r = 0; r < 16; ++r) { sacc[0][r] = 0.f; sacc[1][r] = 0.f; }
    #pragma unroll
    for (int ks = 0; ks < 4; ++ks) {
      const int pc = ((2 * ks + hi) ^ swz) << 3;
      bf16x8 kf0 = *(const bf16x8*)(KtC + (l31)      * 64 + pc);
      bf16x8 kf1 = *(const bf16x8*)(KtC + (32 + l31) * 64 + pc);
      __builtin_amdgcn_s_setprio(1);
      sacc[0] = __builtin_amdgcn_mfma_f32_32x32x16_bf16(kf0, qB[ks], sacc[0], 0, 0, 0);
      sacc[1] = __builtin_amdgcn_mfma_f32_32x32x16_bf16(kf1, qB[ks], sacc[1], 0, 0, 0);
      __builtin_amdgcn_s_setprio(0);
    }

    union { unsigned u[4]; bf16x8 v; } pf[4];
    #pragma unroll
    for (int kvf = 0; kvf < 2; ++kvf) {
      float pe[16];
      #pragma unroll
      for (int r = 0; r < 16; ++r) {
        pe[r] = fexp2(sacc[kvf][r]);
        lsum += pe[r];
      }
      #pragma unroll
      for (int sub = 0; sub < 2; ++sub) {
        unsigned a0 = cvt_pk(pe[8 * sub + 0], pe[8 * sub + 1]);
        unsigned b0 = cvt_pk(pe[8 * sub + 4], pe[8 * sub + 5]);
        plane_swap(a0, b0);
        unsigned a1 = cvt_pk(pe[8 * sub + 2], pe[8 * sub + 3]);
        unsigned b1 = cvt_pk(pe[8 * sub + 6], pe[8 * sub + 7]);
        plane_swap(a1, b1);
        pf[2 * kvf + sub].u[0] = a0;
        pf[2 * kvf + sub].u[1] = a1;
        pf[2 * kvf + sub].u[2] = b0;
        pf[2 * kvf + sub].u[3] = b1;
      }
    }

    #pragma unroll
    for (int ks = 0; ks < 4; ++ks) {
      const int pc = ((2 * ks + hi) ^ swz) << 3;
      bf16x8 vf0 = *(const bf16x8*)(VtC + (l31)      * 64 + pc);
      bf16x8 vf1 = *(const bf16x8*)(VtC + (32 + l31) * 64 + pc);
      __builtin_amdgcn_s_setprio(1);
      oacc[0] = __builtin_amdgcn_mfma_f32_32x32x16_bf16(vf0, pf[ks].v, oacc[0], 0, 0, 0);
      oacc[1] = __builtin_amdgcn_mfma_f32_32x32x16_bf16(vf1, pf[ks].v, oacc[1], 0, 0, 0);
      __builtin_amdgcn_s_setprio(0);
    }
  }

  __syncthreads();

  const float ltot = lsum + __shfl_xor(lsum, 32);
  const float inv = 1.f / ltot;
  short* OtW = SM + w * 2176;        // 32 q x 68 per wave; 4*2176=8704 <= 16384
  #pragma unroll
  for (int sf = 0; sf < 2; ++sf)
    #pragma unroll
    for (int c = 0; c < 4; ++c) {
      u32x2 e;
      e[0] = cvt_pk(oacc[sf][4 * c + 0] * inv, oacc[sf][4 * c + 1] * inv);
      e[1] = cvt_pk(oacc[sf][4 * c + 2] * inv, oacc[sf][4 * c + 3] * inv);
      *(u32x2*)(OtW + l31 * 68 + sf * 32 + 8 * c + 4 * hi) = e;
    }
  __builtin_amdgcn_s_barrier();
  #pragma unroll
  for (int i = 0; i < 8; ++i) {
    const int row = i * 4 + (lane >> 4);
    u32x2 v = *(const u32x2*)(OtW + row * 68 + (lane & 15) * 4);
    *(u32x2*)(AO + base + (size_t)(q0 + w * 32 + row) * kE + (lane & 15) * 4) = v;
  }
}

// ---------------- launch ----------------
extern "C" void kernel_launch(void* const* d_in, const int* in_sizes, int n_in,
                              void* d_out, int out_size, void* d_ws, size_t ws_size,
                              hipStream_t stream) {
  const float* x  = (const float*)d_in[0];
  const float* Wk = (const float*)d_in[1];
  const float* Wq = (const float*)d_in[2];
  const float* Wo = (const float*)d_in[3];
  const float* bo = (const float*)d_in[4];
  float* out = (float*)d_out;

  const size_t nXE = (size_t)kRows * kE;  // 8388608
  const size_t nW  = (size_t)kE * kE;     // 1048576

  short* Xb   = (short*)d_ws;
  short* Kb   = Xb   + nXE;
  short* Qb   = Kb   + nXE;
  short* WkqT = Qb   + nXE;          // [2048][1024]
  short* WoT  = WkqT + 2 * nW;
  short* KTb  = (short*)d_out;  // scratch in out (16.8 MB <= 33.5 MB); gemm_bt
                                // fully overwrites out afterwards (stream-ordered)
  short* AO   = Qb;   // reuse: each block reads its own Qb rows into regs first

  prep<<<dim3(8192 + 3 * 1024), 256, 0, stream>>>(
      x, Wk, Wq, Wo, Xb, WkqT, WoT);

  // Fused K(=V)+Q projections, 256^2 8-wave phase-split; Q scaled by
  // E^-0.5 * log2(e); K blocks also emit transposed KT.
  gemm_kq8<<<dim3(256), 512, 0, stream>>>(
      Xb, WkqT, Kb, Qb, KTb, 0.03125f * 1.44269504f);

  attn_kernel<<<dim3(1024), 256, 0, stream>>>(Qb, Kb, KTb, AO);

  gemm_bt<<<dim3(512), 256, 0, stream>>>(
      AO, WoT, out, bo, kRows, kE, kE);
}

// Round 12
// 160.644 us; speedup vs baseline: 1.5188x; 1.0083x over previous
//
#include <hip/hip_runtime.h>
#include <hip/hip_bf16.h>
#include <stdint.h>

// Problem constants
static constexpr int kB = 4;
static constexpr int kT = 2048;
static constexpr int kE = 1024;
static constexpr int kH = 16;
static constexpr int kS = 64;          // head dim
static constexpr int kRows = kB * kT;  // 8192

typedef __attribute__((ext_vector_type(4)))  float    f32x4;
typedef __attribute__((ext_vector_type(16))) float    f32x16;
typedef __attribute__((ext_vector_type(4)))  float    float4v;
typedef __attribute__((ext_vector_type(8)))  __bf16   bf16x8;
typedef __attribute__((ext_vector_type(8)))  short    short8v;
typedef __attribute__((ext_vector_type(4)))  short    short4v;
typedef __attribute__((ext_vector_type(2)))  unsigned u32x2;
typedef __attribute__((ext_vector_type(4)))  unsigned u32x4;

typedef const __attribute__((address_space(1))) void gvoid_t;
typedef __attribute__((address_space(3))) void lvoid_t;

__device__ __forceinline__ short f2bf(float f) {
  union { float f; unsigned u; } c; c.f = f;
  unsigned r = (c.u + 0x7FFFu + ((c.u >> 16) & 1u)) >> 16;
  return (short)(r & 0xFFFFu);
}

__device__ __forceinline__ short bfc(float f) {
  union { __bf16 b; short s; } u; u.b = (__bf16)f; return u.s;
}

// v_cvt_pk_bf16_f32: D[15:0]=bf16(lo), D[31:16]=bf16(hi).
__device__ __forceinline__ unsigned cvt_pk(float lo, float hi) {
  unsigned r;
  asm("v_cvt_pk_bf16_f32 %0, %1, %2" : "=v"(r) : "v"(lo), "v"(hi));
  return r;
}

// v_permlane32_swap_b32: a' = [a.lo, b.lo], b' = [a.hi, b.hi]
__device__ __forceinline__ void plane_swap(unsigned& a, unsigned& b) {
  asm("v_permlane32_swap_b32 %0, %1" : "+v"(a), "+v"(b));
}

#if __has_builtin(__builtin_amdgcn_exp2f)
__device__ __forceinline__ float fexp2(float x) { return __builtin_amdgcn_exp2f(x); }
#else
__device__ __forceinline__ float fexp2(float x) { return exp2f(x); }
#endif

// ---------------- fused prologue: x->bf16 + three W transposes ----------------
__global__ __launch_bounds__(256)
void prep(const float* __restrict__ x, const float* __restrict__ Wk,
          const float* __restrict__ Wq, const float* __restrict__ Wo,
          short* __restrict__ Xb, short* __restrict__ WkqT,
          short* __restrict__ WoT) {
  const int bid = blockIdx.x;
  if (bid < 8192) {
    size_t i = ((size_t)bid * 256 + threadIdx.x) * 4;
    float4v v = *(const float4v*)(x + i);
    short4v o;
    o[0] = f2bf(v[0]); o[1] = f2bf(v[1]); o[2] = f2bf(v[2]); o[3] = f2bf(v[3]);
    *(short4v*)(Xb + i) = o;
    return;
  }
  __shared__ float tile[32][33];
  const int tb = bid - 8192;
  const int which = tb >> 10, t = tb & 1023;
  const float* W = (which == 0) ? Wk : ((which == 1) ? Wq : Wo);
  short* WT = (which == 0) ? WkqT : ((which == 1) ? (WkqT + kE * kE) : WoT);
  const int tx = threadIdx.x & 31, ty = threadIdx.x >> 5;  // 32 x 8
  const int c = (t & 31) * 32, r = (t >> 5) * 32;
  #pragma unroll
  for (int i = ty; i < 32; i += 8)
    tile[i][tx] = W[(size_t)(r + i) * kE + c + tx];
  __syncthreads();
  #pragma unroll
  for (int i = ty; i < 32; i += 8)
    WT[(size_t)(c + i) * kE + r + tx] = f2bf(tile[tx][i]);
}

// ================= 8-wave phase-split GEMM building blocks =================

// stage 256 rows (two 128-row halves) of a [*, kE] bf16 matrix into linear
// [256][64] LDS, source-chunk XOR pre-swizzled. 4 gloads per wave.
__device__ __forceinline__ void kq_stageA(
    const short* __restrict__ gA, short* nA, int wid, int sl, int sc7) {
  #pragma unroll
  for (int h = 0; h < 2; ++h)
    #pragma unroll
    for (int i = 0; i < 2; ++i) {
      const int slot = wid * 2 + i;
      const int row = slot * 8 + sl;           // row within 128-row half
      const int sc = sc7 ^ (row & 7);
      __builtin_amdgcn_global_load_lds(
          (gvoid_t*)(gA + (size_t)(h * 128 + row) * kE + 8 * sc),
          (lvoid_t*)(nA + h * 8192 + slot * 512), 16, 0, 0);
    }
}

// stage 128 rows into linear [128][64] LDS. 2 gloads per wave (8 waves).
__device__ __forceinline__ void bt_stageB(
    const short* __restrict__ gB, short* nB, int wid, int sl, int sc7) {
  #pragma unroll
  for (int i = 0; i < 2; ++i) {
    const int slot = wid * 2 + i;
    const int row = slot * 8 + sl;
    const int sc = sc7 ^ (row & 7);
    __builtin_amdgcn_global_load_lds(
        (gvoid_t*)(gB + (size_t)row * kE + 8 * sc),
        (lvoid_t*)(nB + slot * 512), 16, 0, 0);
  }
}

// ---------------- 256^2 8-wave phase-split K+Q projection GEMM ----------------
__device__ __forceinline__ void kq_tile(
    const short* __restrict__ gA, const short* __restrict__ gB,  // next k-tile
    const short* cA, const short* cB, short* nA, short* nB,
    bool stage, f32x4 (&acc)[8][4],
    int wid, int wm, int wn, int g, int lr, int sl, int sc7) {
  const int swz = lr & 7;
  const short* cAw = cA + wm * 8192;                  // wave's A half-tile
  const short* cBw = cB + (wn >> 1) * 8192;           // wave's B half-tile
  const int brow0 = (wn & 1) * 64;                    // wave's B row base in half
  bf16x8 af[4][2], b0[2][2], b1[2][2];

  // ================= phase 1: quadrant (Mh0, Nh0) =================
  #pragma unroll
  for (int mf = 0; mf < 4; ++mf)
    #pragma unroll
    for (int kk = 0; kk < 2; ++kk)
      af[mf][kk] = *(const bf16x8*)(cAw + (mf * 16 + lr) * 64 + (((4 * kk + g) ^ swz) << 3));
  #pragma unroll
  for (int nf = 0; nf < 2; ++nf)
    #pragma unroll
    for (int kk = 0; kk < 2; ++kk)
      b0[nf][kk] = *(const bf16x8*)(cBw + (brow0 + nf * 16 + lr) * 64 + (((4 * kk + g) ^ swz) << 3));
  if (stage) kq_stageA(gA, nA, wid, sl, sc7);
  asm volatile("" ::: "memory");
  __builtin_amdgcn_s_barrier();
  asm volatile("s_waitcnt lgkmcnt(0)" ::: "memory");
  __builtin_amdgcn_sched_barrier(0);
  __builtin_amdgcn_s_setprio(1);
  #pragma unroll
  for (int mf = 0; mf < 4; ++mf)
    #pragma unroll
    for (int nf = 0; nf < 2; ++nf)
      #pragma unroll
      for (int kk = 0; kk < 2; ++kk)
        acc[mf][nf] = __builtin_amdgcn_mfma_f32_16x16x32_bf16(af[mf][kk], b0[nf][kk], acc[mf][nf], 0, 0, 0);
  __builtin_amdgcn_s_setprio(0);
  asm volatile("" ::: "memory");
  __builtin_amdgcn_s_barrier();

  // ================= phase 2: quadrant (Mh0, Nh1) =================
  #pragma unroll
  for (int nf = 0; nf < 2; ++nf)
    #pragma unroll
    for (int kk = 0; kk < 2; ++kk)
      b1[nf][kk] = *(const bf16x8*)(cBw + (brow0 + 32 + nf * 16 + lr) * 64 + (((4 * kk + g) ^ swz) << 3));
  if (stage) kq_stageA(gB, nB, wid, sl, sc7);
  asm volatile("" ::: "memory");
  __builtin_amdgcn_s_barrier();
  asm volatile("s_waitcnt lgkmcnt(0)" ::: "memory");
  __builtin_amdgcn_sched_barrier(0);
  __builtin_amdgcn_s_setprio(1);
  #pragma unroll
  for (int mf = 0; mf < 4; ++mf)
    #pragma unroll
    for (int nf = 0; nf < 2; ++nf)
      #pragma unroll
      for (int kk = 0; kk < 2; ++kk)
        acc[mf][2 + nf] = __builtin_amdgcn_mfma_f32_16x16x32_bf16(af[mf][kk], b1[nf][kk], acc[mf][2 + nf], 0, 0, 0);
  __builtin_amdgcn_s_setprio(0);
  asm volatile("" ::: "memory");
  __builtin_amdgcn_s_barrier();

  // ================= phase 3: quadrant (Mh1, Nh1) =================
  #pragma unroll
  for (int mf = 0; mf < 4; ++mf)
    #pragma unroll
    for (int kk = 0; kk < 2; ++kk)
      af[mf][kk] = *(const bf16x8*)(cAw + (64 + mf * 16 + lr) * 64 + (((4 * kk + g) ^ swz) << 3));
  asm volatile("" ::: "memory");
  __builtin_amdgcn_s_barrier();
  asm volatile("s_waitcnt lgkmcnt(0)" ::: "memory");
  __builtin_amdgcn_sched_barrier(0);
  __builtin_amdgcn_s_setprio(1);
  #pragma unroll
  for (int mf = 0; mf < 4; ++mf)
    #pragma unroll
    for (int nf = 0; nf < 2; ++nf)
      #pragma unroll
      for (int kk = 0; kk < 2; ++kk)
        acc[4 + mf][2 + nf] = __builtin_amdgcn_mfma_f32_16x16x32_bf16(af[mf][kk], b1[nf][kk], acc[4 + mf][2 + nf], 0, 0, 0);
  __builtin_amdgcn_s_setprio(0);
  asm volatile("" ::: "memory");
  __builtin_amdgcn_s_barrier();

  // ================= phase 4: quadrant (Mh1, Nh0) =================
  #pragma unroll
  for (int nf = 0; nf < 2; ++nf)
    #pragma unroll
    for (int kk = 0; kk < 2; ++kk)
      b0[nf][kk] = *(const bf16x8*)(cBw + (brow0 + nf * 16 + lr) * 64 + (((4 * kk + g) ^ swz) << 3));
  asm volatile("s_waitcnt vmcnt(0)" ::: "memory");   // next tile's stages landed
  asm volatile("" ::: "memory");
  __builtin_amdgcn_s_barrier();
  asm volatile("s_waitcnt lgkmcnt(0)" ::: "memory");
  __builtin_amdgcn_sched_barrier(0);
  __builtin_amdgcn_s_setprio(1);
  #pragma unroll
  for (int mf = 0; mf < 4; ++mf)
    #pragma unroll
    for (int nf = 0; nf < 2; ++nf)
      #pragma unroll
      for (int kk = 0; kk < 2; ++kk)
        acc[4 + mf][nf] = __builtin_amdgcn_mfma_f32_16x16x32_bf16(af[mf][kk], b0[nf][kk], acc[4 + mf][nf], 0, 0, 0);
  __builtin_amdgcn_s_setprio(0);
  asm volatile("" ::: "memory");
  __builtin_amdgcn_s_barrier();
}

__global__ __launch_bounds__(512)
void gemm_kq8(const short* __restrict__ A, const short* __restrict__ BT,
              short* __restrict__ Kb, short* __restrict__ Qb,
              short* __restrict__ KT, float qs) {
  __shared__ short LA[2][16384];   // 64 KB: A tiles (256x64 per buf)
  __shared__ short LB[2][16384];   // 64 KB: B tiles

  const int tid = threadIdx.x;
  const int wid = tid >> 6, lane = tid & 63;
  const int g = lane >> 4, lr = lane & 15;
  const int wm = wid >> 2, wn = wid & 3;    // 2M x 4N waves
  const int sl = lane >> 3, sc7 = lane & 7;
  const int bid = blockIdx.x;
  const int id = (bid & 7) * 32 + (bid >> 3);   // XCD swizzle (256 % 8 == 0)
  const int n0 = (id & 7) * 256, m0 = (id >> 3) * 256;

  const short* Abase = A + (size_t)m0 * kE;
  const short* Bbase = BT + (size_t)n0 * kE;

  f32x4 acc[8][4];
  #pragma unroll
  for (int mf = 0; mf < 8; ++mf)
    #pragma unroll
    for (int nf = 0; nf < 4; ++nf)
      #pragma unroll
      for (int r = 0; r < 4; ++r) acc[mf][nf][r] = 0.f;

  // ---- prologue: stage K-tile 0 into buf 0, full drain (one-time) ----
  kq_stageA(Abase, &LA[0][0], wid, sl, sc7);
  kq_stageA(Bbase, &LB[0][0], wid, sl, sc7);
  asm volatile("s_waitcnt vmcnt(0)" ::: "memory");
  __syncthreads();

  // ---- main loop: 16 K-tiles, 2 per iteration (static dbuf indices) ----
  for (int ktp = 0; ktp < 8; ++ktp) {
    kq_tile(Abase + (2 * ktp + 1) * 64, Bbase + (2 * ktp + 1) * 64,
            &LA[0][0], &LB[0][0], &LA[1][0], &LB[1][0],
            true, acc, wid, wm, wn, g, lr, sl, sc7);
    kq_tile(Abase + (2 * ktp + 2) * 64, Bbase + (2 * ktp + 2) * 64,
            &LA[1][0], &LB[1][0], &LA[0][0], &LB[0][0],
            (2 * ktp + 1) < 15, acc, wid, wm, wn, g, lr, sl, sc7);
  }

  // ---- epilogue ----
  const int isq = (n0 >= 1024);
  short* Crm = isq ? Qb : Kb;
  const float scale = isq ? qs : 1.0f;
  const int crow = m0 + wm * 128, ccol = (n0 & 1023) + wn * 64;
  #pragma unroll
  for (int mf = 0; mf < 8; ++mf)
    #pragma unroll
    for (int nf = 0; nf < 4; ++nf)
      #pragma unroll
      for (int r = 0; r < 4; ++r)
        Crm[(size_t)(crow + mf * 16 + 4 * g + r) * kE + ccol + nf * 16 + lr] =
            bfc(acc[mf][nf][r] * scale);
  if (!isq) {
    // transposed copy KT[(b*16+h)*64 + s][t]  (r-packed 8B stores)
    const int b = m0 >> 11, tloc = (m0 & 2047) + wm * 128;
    const int h = (n0 + wn * 64) >> 6;
    #pragma unroll
    for (int mf = 0; mf < 8; ++mf)
      #pragma unroll
      for (int nf = 0; nf < 4; ++nf) {
        u32x2 e;
        e[0] = cvt_pk(acc[mf][nf][0], acc[mf][nf][1]);
        e[1] = cvt_pk(acc[mf][nf][2], acc[mf][nf][3]);
        *(u32x2*)(KT + (size_t)((b * 16 + h) * 64 + nf * 16 + lr) * kT +
                  tloc + mf * 16 + 4 * g) = e;
      }
  }
}

// ---------------- 256x128 8-wave phase-split output GEMM (f32 + bias) ----------------
// BM=256, BN=128, BK=64, 512 threads (4M x 2N waves, wave tile 64x64).
// Same 4-phase skeleton as kq_tile; p4 keeps b0 live (no re-read).
__global__ __launch_bounds__(512)
void gemm_bt8(const short* __restrict__ A, const short* __restrict__ BT,
              float* __restrict__ C, const float* __restrict__ bias) {
  __shared__ short LA[2][16384];   // 64 KB: A tiles (256x64)
  __shared__ short LB[2][8192];    // 32 KB: B tiles (128x64)

  const int tid = threadIdx.x;
  const int wid = tid >> 6, lane = tid & 63;
  const int g = lane >> 4, lr = lane & 15;
  const int wm = wid >> 1, wn = wid & 1;    // 4M x 2N waves
  const int sl = lane >> 3, sc7 = lane & 7;
  const int swz = lr & 7;
  const int bid = blockIdx.x;
  const int id = (bid & 7) * 32 + (bid >> 3);   // XCD swizzle (256 % 8 == 0)
  const int n0 = (id & 7) * 128, m0 = (id >> 3) * 256;

  const short* Abase = A + (size_t)m0 * kE;
  const short* Bbase = BT + (size_t)n0 * kE;

  f32x4 acc[4][4];
  #pragma unroll
  for (int mf = 0; mf < 4; ++mf)
    #pragma unroll
    for (int nf = 0; nf < 4; ++nf)
      #pragma unroll
      for (int r = 0; r < 4; ++r) acc[mf][nf][r] = 0.f;

  kq_stageA(Abase, &LA[0][0], wid, sl, sc7);
  bt_stageB(Bbase, &LB[0][0], wid, sl, sc7);
  asm volatile("s_waitcnt vmcnt(0)" ::: "memory");
  __syncthreads();

  for (int ktp = 0; ktp < 8; ++ktp) {
    #pragma unroll
    for (int half = 0; half < 2; ++half) {
      const int kt = 2 * ktp + half;
      const short* cA = &LA[kt & 1][0];
      const short* cB = &LB[kt & 1][0];
      short* nA = &LA[(kt + 1) & 1][0];
      short* nB = &LB[(kt + 1) & 1][0];
      const bool stage = kt < 15;
      const short* gA = Abase + (kt + 1) * 64;
      const short* gB = Bbase + (kt + 1) * 64;
      const short* cAw = cA + wm * 4096;   // wave's 64 A-rows
      const short* cBw = cB + wn * 4096;   // wave's 64 B-rows
      bf16x8 af[2][2], b0[2][2], b1[2][2];

      // ---- phase 1: (Mh0, Nh0) ----
      #pragma unroll
      for (int mf = 0; mf < 2; ++mf)
        #pragma unroll
        for (int kk = 0; kk < 2; ++kk)
          af[mf][kk] = *(const bf16x8*)(cAw + (mf * 16 + lr) * 64 + (((4 * kk + g) ^ swz) << 3));
      #pragma unroll
      for (int nf = 0; nf < 2; ++nf)
        #pragma unroll
        for (int kk = 0; kk < 2; ++kk)
          b0[nf][kk] = *(const bf16x8*)(cBw + (nf * 16 + lr) * 64 + (((4 * kk + g) ^ swz) << 3));
      if (stage) kq_stageA(gA, nA, wid, sl, sc7);
      asm volatile("" ::: "memory");
      __builtin_amdgcn_s_barrier();
      asm volatile("s_waitcnt lgkmcnt(0)" ::: "memory");
      __builtin_amdgcn_sched_barrier(0);
      __builtin_amdgcn_s_setprio(1);
      #pragma unroll
      for (int mf = 0; mf < 2; ++mf)
        #pragma unroll
        for (int nf = 0; nf < 2; ++nf)
          #pragma unroll
          for (int kk = 0; kk < 2; ++kk)
            acc[mf][nf] = __builtin_amdgcn_mfma_f32_16x16x32_bf16(af[mf][kk], b0[nf][kk], acc[mf][nf], 0, 0, 0);
      __builtin_amdgcn_s_setprio(0);
      asm volatile("" ::: "memory");
      __builtin_amdgcn_s_barrier();

      // ---- phase 2: (Mh0, Nh1) ----
      #pragma unroll
      for (int nf = 0; nf < 2; ++nf)
        #pragma unroll
        for (int kk = 0; kk < 2; ++kk)
          b1[nf][kk] = *(const bf16x8*)(cBw + (32 + nf * 16 + lr) * 64 + (((4 * kk + g) ^ swz) << 3));
      if (stage) bt_stageB(gB, nB, wid, sl, sc7);
      asm volatile("" ::: "memory");
      __builtin_amdgcn_s_barrier();
      asm volatile("s_waitcnt lgkmcnt(0)" ::: "memory");
      __builtin_amdgcn_sched_barrier(0);
      __builtin_amdgcn_s_setprio(1);
      #pragma unroll
      for (int mf = 0; mf < 2; ++mf)
        #pragma unroll
        for (int nf = 0; nf < 2; ++nf)
          #pragma unroll
          for (int kk = 0; kk < 2; ++kk)
            acc[mf][2 + nf] = __builtin_amdgcn_mfma_f32_16x16x32_bf16(af[mf][kk], b1[nf][kk], acc[mf][2 + nf], 0, 0, 0);
      __builtin_amdgcn_s_setprio(0);
      asm volatile("" ::: "memory");
      __builtin_amdgcn_s_barrier();

      // ---- phase 3: (Mh1, Nh1) ----
      #pragma unroll
      for (int mf = 0; mf < 2; ++mf)
        #pragma unroll
        for (int kk = 0; kk < 2; ++kk)
          af[mf][kk] = *(const bf16x8*)(cAw + (32 + mf * 16 + lr) * 64 + (((4 * kk + g) ^ swz) << 3));
      asm volatile("" ::: "memory");
      __builtin_amdgcn_s_barrier();
      asm volatile("s_waitcnt lgkmcnt(0)" ::: "memory");
      __builtin_amdgcn_sched_barrier(0);
      __builtin_amdgcn_s_setprio(1);
      #pragma unroll
      for (int mf = 0; mf < 2; ++mf)
        #pragma unroll
        for (int nf = 0; nf < 2; ++nf)
          #pragma unroll
          for (int kk = 0; kk < 2; ++kk)
            acc[2 + mf][2 + nf] = __builtin_amdgcn_mfma_f32_16x16x32_bf16(af[mf][kk], b1[nf][kk], acc[2 + mf][2 + nf], 0, 0, 0);
      __builtin_amdgcn_s_setprio(0);
      asm volatile("" ::: "memory");
      __builtin_amdgcn_s_barrier();

      // ---- phase 4: (Mh1, Nh0) — b0 still live; drain next-tile stages ----
      asm volatile("s_waitcnt vmcnt(0)" ::: "memory");
      asm volatile("" ::: "memory");
      __builtin_amdgcn_s_barrier();
      __builtin_amdgcn_sched_barrier(0);
      __builtin_amdgcn_s_setprio(1);
      #pragma unroll
      for (int mf = 0; mf < 2; ++mf)
        #pragma unroll
        for (int nf = 0; nf < 2; ++nf)
          #pragma unroll
          for (int kk = 0; kk < 2; ++kk)
            acc[2 + mf][nf] = __builtin_amdgcn_mfma_f32_16x16x32_bf16(af[mf][kk], b0[nf][kk], acc[2 + mf][nf], 0, 0, 0);
      __builtin_amdgcn_s_setprio(0);
      asm volatile("" ::: "memory");
      __builtin_amdgcn_s_barrier();
    }
  }

  const int crow = m0 + wm * 64, ccol = n0 + wn * 64;
  float bv[4];
  #pragma unroll
  for (int nf = 0; nf < 4; ++nf) bv[nf] = bias[ccol + nf * 16 + lr];
  #pragma unroll
  for (int mf = 0; mf < 4; ++mf)
    #pragma unroll
    for (int nf = 0; nf < 4; ++nf)
      #pragma unroll
      for (int r = 0; r < 4; ++r)
        C[(size_t)(crow + mf * 16 + 4 * g + r) * kE + ccol + nf * 16 + lr] =
            acc[mf][nf][r] + bv[nf];
}

// ---------------- flash attention; V == K (faithful to reference bug) ----------------
// 32x32 swapped structure. STATIC softmax m=0 (shift-invariant; |s| < ~2 here).
// Q pre-scaled by E^-0.5 * log2(e) so P = exp2(s').
// l MUST be the f32 lsum + shfl_xor(32) path (ones-MFMA l failed on HW twice:
// R6/R8 at 1.9e-2 - do not reintroduce).
__global__ __launch_bounds__(256, 4)
void attn_kernel(const short* Qb, const short* __restrict__ Kb,
                 const short* __restrict__ KT, short* AO) {
  __shared__ short SM[16384];   // 32 KB: Kt[2] @ 0/4096, Vt[2] @ 8192/12288

  const int tid = threadIdx.x;
  const int w = tid >> 6, lane = tid & 63;
  const int l31 = lane & 31, hi = lane >> 5;
  const int swz = l31 & 7;
  const int bid = blockIdx.x;
  const int id = (bid & 7) * 128 + (bid >> 3);  // XCD swizzle (1024 % 8 == 0)
  const int q0 = (id & 15) * 128;
  const int bh = id >> 4;                       // b*16 + h
  const size_t base = (size_t)(bh >> 4) * kT * kE + (size_t)(bh & 15) * kS;
  const short* Kbh = Kb + base;
  const short* KTbh = KT + (size_t)bh * 64 * kT;

  const int srow_lo = lane >> 3, sch = lane & 7;

  #pragma unroll
  for (int i = 0; i < 2; ++i) {
    const int slot = w * 2 + i, row = slot * 8 + srow_lo;
    const int sc = sch ^ (row & 7);
    __builtin_amdgcn_global_load_lds(
        (gvoid_t*)(Kbh + (size_t)row * kE + 8 * sc),
        (lvoid_t*)(SM + slot * 512), 16, 0, 0);
    __builtin_amdgcn_global_load_lds(
        (gvoid_t*)(KTbh + (size_t)row * kT + 8 * sc),
        (lvoid_t*)(SM + 8192 + slot * 512), 16, 0, 0);
  }

  bf16x8 qB[4];
  #pragma unroll
  for (int ks = 0; ks < 4; ++ks)
    qB[ks] = *(const bf16x8*)(Qb + base +
        (size_t)(q0 + w * 32 + l31) * kE + ks * 16 + hi * 8);

  f32x16 oacc[2];
  #pragma unroll
  for (int r = 0; r < 16; ++r) { oacc[0][r] = 0.f; oacc[1][r] = 0.f; }
  float lsum = 0.f;

  for (int t = 0; t < 32; ++t) {
    __syncthreads();

    if (t < 31) {
      const short* kbt = Kbh + (size_t)(t + 1) * 64 * kE;
      const short* vtt = KTbh + (size_t)(t + 1) * 64;
      short* KtN = SM + ((t + 1) & 1) * 4096;
      short* VtN = SM + 8192 + ((t + 1) & 1) * 4096;
      #pragma unroll
      for (int i = 0; i < 2; ++i) {
        const int slot = w * 2 + i, row = slot * 8 + srow_lo;
        const int sc = sch ^ (row & 7);
        __builtin_amdgcn_global_load_lds(
            (gvoid_t*)(kbt + (size_t)row * kE + 8 * sc),
            (lvoid_t*)(KtN + slot * 512), 16, 0, 0);
        __builtin_amdgcn_global_load_lds(
            (gvoid_t*)(vtt + (size_t)row * kT + 8 * sc),
            (lvoid_t*)(VtN + slot * 512), 16, 0, 0);
      }
    }

    const short* KtC = SM + (t & 1) * 4096;
    const short* VtC = SM + 8192 + (t & 1) * 4096;

    f32x16 sacc[2];
    #pragma unroll
    for (int r = 0; r < 16; ++r) { sacc[0][r] = 0.f; sacc[1][r] = 0.f; }
    #pragma unroll
    for (int ks = 0; ks < 4; ++ks) {
      const int pc = ((2 * ks + hi) ^ swz) << 3;
      bf16x8 kf0 = *(const bf16x8*)(KtC + (l31)      * 64 + pc);
      bf16x8 kf1 = *(const bf16x8*)(KtC + (32 + l31) * 64 + pc);
      __builtin_amdgcn_s_setprio(1);
      sacc[0] = __builtin_amdgcn_mfma_f32_32x32x16_bf16(kf0, qB[ks], sacc[0], 0, 0, 0);
      sacc[1] = __builtin_amdgcn_mfma_f32_32x32x16_bf16(kf1, qB[ks], sacc[1], 0, 0, 0);
      __builtin_amdgcn_s_setprio(0);
    }

    union { unsigned u[4]; bf16x8 v; } pf[4];
    #pragma unroll
    for (int kvf = 0; kvf < 2; ++kvf) {
      float pe[16];
      #pragma unroll
      for (int r = 0; r < 16; ++r) {
        pe[r] = fexp2(sacc[kvf][r]);
        lsum += pe[r];
      }
      #pragma unroll
      for (int sub = 0; sub < 2; ++sub) {
        unsigned a0 = cvt_pk(pe[8 * sub + 0], pe[8 * sub + 1]);
        unsigned b0 = cvt_pk(pe[8 * sub + 4], pe[8 * sub + 5]);
        plane_swap(a0, b0);
        unsigned a1 = cvt_pk(pe[8 * sub + 2], pe[8 * sub + 3]);
        unsigned b1 = cvt_pk(pe[8 * sub + 6], pe[8 * sub + 7]);
        plane_swap(a1, b1);
        pf[2 * kvf + sub].u[0] = a0;
        pf[2 * kvf + sub].u[1] = a1;
        pf[2 * kvf + sub].u[2] = b0;
        pf[2 * kvf + sub].u[3] = b1;
      }
    }

    #pragma unroll
    for (int ks = 0; ks < 4; ++ks) {
      const int pc = ((2 * ks + hi) ^ swz) << 3;
      bf16x8 vf0 = *(const bf16x8*)(VtC + (l31)      * 64 + pc);
      bf16x8 vf1 = *(const bf16x8*)(VtC + (32 + l31) * 64 + pc);
      __builtin_amdgcn_s_setprio(1);
      oacc[0] = __builtin_amdgcn_mfma_f32_32x32x16_bf16(vf0, pf[ks].v, oacc[0], 0, 0, 0);
      oacc[1] = __builtin_amdgcn_mfma_f32_32x32x16_bf16(vf1, pf[ks].v, oacc[1], 0, 0, 0);
      __builtin_amdgcn_s_setprio(0);
    }
  }

  __syncthreads();

  const float ltot = lsum + __shfl_xor(lsum, 32);
  const float inv = 1.f / ltot;
  short* OtW = SM + w * 2176;        // 32 q x 68 per wave; 4*2176=8704 <= 16384
  #pragma unroll
  for (int sf = 0; sf < 2; ++sf)
    #pragma unroll
    for (int c = 0; c < 4; ++c) {
      u32x2 e;
      e[0] = cvt_pk(oacc[sf][4 * c + 0] * inv, oacc[sf][4 * c + 1] * inv);
      e[1] = cvt_pk(oacc[sf][4 * c + 2] * inv, oacc[sf][4 * c + 3] * inv);
      *(u32x2*)(OtW + l31 * 68 + sf * 32 + 8 * c + 4 * hi) = e;
    }
  __builtin_amdgcn_s_barrier();
  #pragma unroll
  for (int i = 0; i < 8; ++i) {
    const int row = i * 4 + (lane >> 4);
    u32x2 v = *(const u32x2*)(OtW + row * 68 + (lane & 15) * 4);
    *(u32x2*)(AO + base + (size_t)(q0 + w * 32 + row) * kE + (lane & 15) * 4) = v;
  }
}

// ---------------- launch ----------------
extern "C" void kernel_launch(void* const* d_in, const int* in_sizes, int n_in,
                              void* d_out, int out_size, void* d_ws, size_t ws_size,
                              hipStream_t stream) {
  const float* x  = (const float*)d_in[0];
  const float* Wk = (const float*)d_in[1];
  const float* Wq = (const float*)d_in[2];
  const float* Wo = (const float*)d_in[3];
  const float* bo = (const float*)d_in[4];
  float* out = (float*)d_out;

  const size_t nXE = (size_t)kRows * kE;  // 8388608
  const size_t nW  = (size_t)kE * kE;     // 1048576

  short* Xb   = (short*)d_ws;
  short* Kb   = Xb   + nXE;
  short* Qb   = Kb   + nXE;
  short* WkqT = Qb   + nXE;          // [2048][1024]
  short* WoT  = WkqT + 2 * nW;
  short* KTb  = (short*)d_out;  // scratch in out (16.8 MB <= 33.5 MB); gemm_bt8
                                // fully overwrites out afterwards (stream-ordered)
  short* AO   = Qb;   // reuse: each block reads its own Qb rows into regs first

  prep<<<dim3(8192 + 3 * 1024), 256, 0, stream>>>(
      x, Wk, Wq, Wo, Xb, WkqT, WoT);

  gemm_kq8<<<dim3(256), 512, 0, stream>>>(
      Xb, WkqT, Kb, Qb, KTb, 0.03125f * 1.44269504f);

  attn_kernel<<<dim3(1024), 256, 0, stream>>>(Qb, Kb, KTb, AO);

  gemm_bt8<<<dim3(256), 512, 0, stream>>>(AO, WoT, out, bo);
}